// Round 13
// baseline (647.021 us; speedup 1.0000x reference)
//
#include <hip/hip_runtime.h>
#include <math.h>

// ---- problem constants ----
#define NTOK    4096      // B*S
#define DMODEL  512
#define NEXP    32
#define RRANK   64
#define HEXP    512
#define HSHARED 4096
#define SEQ     1024
#define BATCH   4
#define NHEAD   8
#define TOPK    4
#define NLAYER  2
#define QBLK    64
#define KBLK    64
#define MAXTILE 160       // max padded expert m-tiles: 16384/128 + 32

typedef __attribute__((ext_vector_type(8))) short bf16x8;
typedef __attribute__((ext_vector_type(4))) float f32x4;

__device__ __forceinline__ float gelu_f(float x) {
    float t = tanhf(0.7978845608028654f * (x + 0.044715f * x * x * x));
    return 0.5f * x * (1.f + t);
}
__device__ __forceinline__ unsigned short f2bf(float f) {
    unsigned int u = __float_as_uint(f);
    u += 0x7FFFu + ((u >> 16) & 1u);
    return (unsigned short)(u >> 16);
}
__device__ __forceinline__ float bf2f(unsigned short u) {
    return __uint_as_float((unsigned int)u << 16);
}
// async global->LDS, 16B per lane; LDS dest wave-uniform base + lane*16
__device__ __forceinline__ void gl_lds16(const void* g, void* l) {
    __builtin_amdgcn_global_load_lds(
        (const __attribute__((address_space(1))) void*)g,
        (__attribute__((address_space(3))) void*)l, 16, 0, 0);
}

// ---------------- LayerNorm: one wave per row of 512; MODE 0=f32, 1=bf16, 2=both ----------------
template <int MODE>
__global__ __launch_bounds__(256) void ln_kernel(const float* __restrict__ x,
                                                 const float* __restrict__ s,
                                                 const float* __restrict__ b,
                                                 float* __restrict__ outf,
                                                 unsigned short* __restrict__ outb) {
    int wave = threadIdx.x >> 6, lane = threadIdx.x & 63;
    int row = blockIdx.x * 4 + wave;
    const float* xr = x + (size_t)row * DMODEL;
    float v[8];
    float sum = 0.f;
#pragma unroll
    for (int i = 0; i < 8; i++) { v[i] = xr[lane + i * 64]; sum += v[i]; }
#pragma unroll
    for (int o = 32; o; o >>= 1) sum += __shfl_xor(sum, o);
    float m = sum * (1.f / DMODEL);
    float vs = 0.f;
#pragma unroll
    for (int i = 0; i < 8; i++) { float d = v[i] - m; vs += d * d; }
#pragma unroll
    for (int o = 32; o; o >>= 1) vs += __shfl_xor(vs, o);
    float rstd = rsqrtf(vs * (1.f / DMODEL) + 1e-5f);
#pragma unroll
    for (int i = 0; i < 8; i++) {
        int c = lane + i * 64;
        float r = (v[i] - m) * rstd * s[c] + b[c];
        if (MODE != 1) outf[(size_t)row * DMODEL + c] = r;
        if (MODE != 0) outb[(size_t)row * DMODEL + c] = f2bf(r);
    }
}

// ---------------- weight transpose + fp32->bf16: src [K][N] -> dst [N][K] bf16 ----------------
__global__ __launch_bounds__(256) void wt_kernel(const float* __restrict__ src,
                                                 unsigned short* __restrict__ dst,
                                                 int K, int N) {
    src += (size_t)blockIdx.z * K * N;
    dst += (size_t)blockIdx.z * K * N;
    __shared__ float t[64][68];
    int k0 = blockIdx.y * 64, n0 = blockIdx.x * 64;
    int tid = threadIdx.x;
    int r = tid >> 2;
    int cb = (tid & 3) * 4;
#pragma unroll
    for (int i = 0; i < 4; i++)
        *(float4*)&t[r][cb + i * 16] = *(const float4*)(src + (size_t)(k0 + r) * N + n0 + cb + i * 16);
    __syncthreads();
    int g = tid & 7;
    int nr = tid >> 3;
#pragma unroll
    for (int i = 0; i < 2; i++) {
        int n = nr + i * 32;
        bf16x8 v;
#pragma unroll
        for (int j = 0; j < 8; j++) v[j] = (short)f2bf(t[g * 8 + j][n]);
        *(bf16x8*)(dst + (size_t)(n0 + n) * K + k0 + g * 8) = v;
    }
}

// ---------------- bias pack: [bq|bk|bv] -> bqkv[1536] ----------------
__global__ __launch_bounds__(256) void biaspack(const float* __restrict__ a,
                                                const float* __restrict__ b,
                                                const float* __restrict__ c,
                                                float* __restrict__ dst) {
    int i = blockIdx.x * 256 + threadIdx.x;
    float v = (i < 512) ? a[i] : (i < 1024 ? b[i - 512] : c[i - 1024]);
    dst[i] = v;
}

// ---------------- V transpose: qkv[.,1024+h*64+d] -> Vt[b,h,d,s] (bf16) ----------------
__global__ __launch_bounds__(256) void vtr_kernel(const unsigned short* __restrict__ QKV,
                                                  unsigned short* __restrict__ Vt) {
    int st = blockIdx.x, hh = blockIdx.y, bb = blockIdx.z;
    __shared__ unsigned short t[64][72];
    int r = threadIdx.x >> 3, g = threadIdx.x & 7;
#pragma unroll
    for (int i = 0; i < 2; i++) {
        int row = r + i * 32;
        bf16x8 v = *(const bf16x8*)(QKV + (size_t)(bb * SEQ + st * 64 + row) * 1536 + 1024 + hh * 64 + g * 8);
        *(bf16x8*)&t[row][g * 8] = v;
    }
    __syncthreads();
#pragma unroll
    for (int i = 0; i < 2; i++) {
        int d = r + i * 32;
        bf16x8 v;
#pragma unroll
        for (int j = 0; j < 8; j++) v[j] = (short)t[g * 8 + j][d];
        *(bf16x8*)(Vt + (size_t)((bb * NHEAD + hh) * 64 + d) * SEQ + st * 64 + g * 8) = v;
    }
}

// ---------------- bf16 MFMA GEMM: 128x64 tile, templated BK (64 or 128) ----------------
// BK=128 for K-rich GEMMs: halves barrier/drain count per block; LDS 48KB -> 3 blocks/CU.
// Swizzle generalizes: RS-byte rows, CH 16B-chunks, byte ^= (row & (CH-1))<<4 applied BOTH
// to pre-swizzled global source (per-issue) and ds_read (rule #21).
template <bool GELU, bool DORES, bool GATHER, bool EXPERT, bool OUTBF16, int SK = 1, int BK = 64>
__global__ __launch_bounds__(256, 2) void gemm_mfma(
    const unsigned short* __restrict__ Ab, const unsigned short* __restrict__ Wt,
    const float* __restrict__ bias, const float* __restrict__ res,
    void* __restrict__ Cvoid, int M, int Nn, int Kk,
    const int* __restrict__ rowmap, const int* __restrict__ cntp,
    const int* __restrict__ offp, const int* __restrict__ tinfo) {
    constexpr int RS  = BK * 2;        // row stride bytes
    constexpr int CH  = RS / 16;       // 16B chunks per row (8 / 16)
    constexpr int RPI = 1024 / RS;     // rows per gl_lds issue (8 / 4)
    constexpr int AIW = 32 / RPI;      // A issues per wave
    constexpr int BIW = 16 / RPI;      // B issues per wave
    unsigned int bid = blockIdx.y * gridDim.x + blockIdx.x;
    unsigned int tot = gridDim.x * gridDim.y;
    unsigned int lg = (bid & 7) * (tot >> 3) + (bid >> 3);
    unsigned int bx = lg % gridDim.x;
    unsigned int by = lg / gridDim.x;
    int n0 = bx * 64;
    int m0;
    size_t cbase = 0;
    int kbeg = 0, kend = Kk;
    if (EXPERT) {
        int t = by;
        if (t >= tinfo[0]) return;
        int e = tinfo[1 + 2 * t];
        m0 = tinfo[2 + 2 * t];
        M = cntp[e];
        Wt += (size_t)e * Nn * Kk;
        bias += (size_t)e * Nn;
        int oe = offp[e];
        cbase = (size_t)oe * Nn;
        if (GATHER) rowmap += oe;
        else Ab += (size_t)oe * Kk;
    } else {
        m0 = by * 128;
    }
    if (SK > 1) {
        int s = blockIdx.z;
        int chunk = Kk / SK;
        kbeg = s * chunk;
        kend = kbeg + chunk;
        cbase = (size_t)s * M * Nn;
    }
    __shared__ short As[128 * BK];
    __shared__ short Bs[64 * BK];
    char* asb = (char*)As;
    char* bsb = (char*)Bs;
    int tid = threadIdx.x;
    int wave = tid >> 6, lane = tid & 63;
    int wm = wave >> 1, wn = wave & 1;
    int l15 = lane & 15, l16 = lane >> 4;
    int c16 = lane & (CH - 1);                  // chunk index within row
    int ro  = lane / CH;                        // row offset within issue

    // hoisted per-lane source pointers (k-independent; rowmap gather ONCE; per-issue swizzle)
    const char* aptr[AIW];
    const char* bptr[BIW];
#pragma unroll
    for (int j = 0; j < AIW; j++) {
        int rloc = j * RPI + ro;                // 0..31 within wave's A chunk
        int row = wave * 32 + rloc;
        int grow = m0 + row;
        int arow = GATHER ? rowmap[grow] : grow;   // pad rows: rowmap=0 (memset), output discarded
        int srcoff = ((c16 ^ (rloc & (CH - 1))) << 4);
        aptr[j] = (const char*)Ab + (((size_t)arow * Kk) << 1) + srcoff;
    }
#pragma unroll
    for (int j = 0; j < BIW; j++) {
        int rloc = j * RPI + ro;                // 0..15 within wave's B chunk
        int row = wave * 16 + rloc;
        int srcoff = ((c16 ^ (rloc & (CH - 1))) << 4);
        bptr[j] = (const char*)Wt + (((size_t)(n0 + row) * Kk) << 1) + srcoff;
    }

    f32x4 acc[4][2];
#pragma unroll
    for (int m = 0; m < 4; m++)
#pragma unroll
        for (int n = 0; n < 2; n++)
#pragma unroll
            for (int j = 0; j < 4; j++) acc[m][n][j] = 0.f;

    for (int k0 = kbeg; k0 < kend; k0 += BK) {
        size_t kb = (size_t)k0 << 1;
#pragma unroll
        for (int j = 0; j < AIW; j++) gl_lds16(aptr[j] + kb, asb + wave * 32 * RS + j * 1024);
#pragma unroll
        for (int j = 0; j < BIW; j++) gl_lds16(bptr[j] + kb, bsb + wave * 16 * RS + j * 1024);
        __syncthreads();   // drains vmcnt -> LDS writes visible
#pragma unroll
        for (int kk = 0; kk < BK / 32; kk++) {
            int k8 = kk * 4 + l16;
            bf16x8 a[4], b[2];
#pragma unroll
            for (int m = 0; m < 4; m++) {
                int row = wm * 64 + m * 16 + l15;
                a[m] = *(const bf16x8*)(asb + row * RS + ((k8 * 16) ^ ((row & (CH - 1)) << 4)));
            }
#pragma unroll
            for (int n = 0; n < 2; n++) {
                int row = wn * 32 + n * 16 + l15;
                b[n] = *(const bf16x8*)(bsb + row * RS + ((k8 * 16) ^ ((row & (CH - 1)) << 4)));
            }
#pragma unroll
            for (int m = 0; m < 4; m++)
#pragma unroll
                for (int n = 0; n < 2; n++)
                    acc[m][n] = __builtin_amdgcn_mfma_f32_16x16x32_bf16(a[m], b[n], acc[m][n], 0, 0, 0);
        }
        __syncthreads();
    }

#pragma unroll
    for (int m = 0; m < 4; m++) {
#pragma unroll
        for (int n = 0; n < 2; n++) {
            int col = n0 + wn * 32 + n * 16 + l15;
            float bv = (SK == 1 && bias) ? bias[col] : 0.f;
#pragma unroll
            for (int j = 0; j < 4; j++) {
                int row = m0 + wm * 64 + m * 16 + l16 * 4 + j;
                if (row >= M) continue;
                float val = acc[m][n][j] + bv;
                if (SK == 1 && GELU) val = gelu_f(val);
                if (SK == 1 && DORES) val += res[(size_t)row * Nn + col];
                if (SK == 1 && OUTBF16)
                    ((unsigned short*)Cvoid)[cbase + (size_t)row * Nn + col] = f2bf(val);
                else
                    ((float*)Cvoid)[cbase + (size_t)row * Nn + col] = val;
            }
        }
    }
}

// ---------------- split-K reduce (+bias +residual, optional MoE combine) ----------------
template <int SK, bool MOE>
__global__ __launch_bounds__(256) void reduce_kernel(
    const float* __restrict__ pbuf, const float* __restrict__ bias,
    const unsigned short* __restrict__ eogb, const float* __restrict__ topw,
    const int* __restrict__ pos, float* __restrict__ xb) {
    int idx = (blockIdx.x * 256 + threadIdx.x) * 4;
    int n = idx >> 9, col = idx & 511;
    float4 v = *(float4*)(xb + idx);
    float4 bv = *(const float4*)(bias + col);
    v.x += bv.x; v.y += bv.y; v.z += bv.z; v.w += bv.w;
#pragma unroll
    for (int s = 0; s < SK; s++) {
        float4 p = *(const float4*)(pbuf + (size_t)s * NTOK * DMODEL + idx);
        v.x += p.x; v.y += p.y; v.z += p.z; v.w += p.w;
    }
    if (MOE) {
#pragma unroll
        for (int k = 0; k < TOPK; k++) {
            float w = topw[n * TOPK + k];
            const unsigned short* e = eogb + (size_t)pos[n * TOPK + k] * DMODEL + col;
            ushort4 u = *(const ushort4*)e;
            v.x += w * bf2f(u.x); v.y += w * bf2f(u.y);
            v.z += w * bf2f(u.z); v.w += w * bf2f(u.w);
        }
    }
    *(float4*)(xb + idx) = v;
}

// ---------------- small fp32 GEMM (router only) ----------------
template <bool GELU>
__global__ __launch_bounds__(256) void gemm_tile(
    const float* __restrict__ A, const float* __restrict__ W,
    float* __restrict__ C, int M, int Nn, int Kk, int lda) {
    int n0 = blockIdx.x * 64;
    int m0 = blockIdx.y * 64;
    __shared__ float Asf[16][68];
    __shared__ float Wsf[16][68];
    int tid = threadIdx.x;
    int ml = tid >> 2, kl = (tid & 3) << 2;
    bool avalid = (m0 + ml) < M;
    int arow = m0 + ml;
    const float* aptr = A + (size_t)arow * lda + kl;
    int kr = tid >> 4, nc = (tid & 15) << 2;
    bool wvalid = (n0 + nc) < Nn;
    const float* wptr = W + (size_t)kr * Nn + n0 + nc;
    int tm = (tid >> 4) << 2, tn = (tid & 15) << 2;
    float acc[4][4] = {{0.f}};
    for (int k0 = 0; k0 < Kk; k0 += 16) {
        float4 av = make_float4(0.f, 0.f, 0.f, 0.f);
        float4 wv = make_float4(0.f, 0.f, 0.f, 0.f);
        if (avalid) av = *(const float4*)(aptr + k0);
        if (wvalid) wv = *(const float4*)(wptr + (size_t)k0 * Nn);
        Asf[kl + 0][ml] = av.x; Asf[kl + 1][ml] = av.y;
        Asf[kl + 2][ml] = av.z; Asf[kl + 3][ml] = av.w;
        *(float4*)&Wsf[kr][nc] = wv;
        __syncthreads();
#pragma unroll
        for (int kk = 0; kk < 16; kk++) {
            float4 a4 = *(const float4*)&Asf[kk][tm];
            float4 w4 = *(const float4*)&Wsf[kk][tn];
            acc[0][0] += a4.x * w4.x; acc[0][1] += a4.x * w4.y; acc[0][2] += a4.x * w4.z; acc[0][3] += a4.x * w4.w;
            acc[1][0] += a4.y * w4.x; acc[1][1] += a4.y * w4.y; acc[1][2] += a4.y * w4.z; acc[1][3] += a4.y * w4.w;
            acc[2][0] += a4.z * w4.x; acc[2][1] += a4.z * w4.y; acc[2][2] += a4.z * w4.z; acc[2][3] += a4.z * w4.w;
            acc[3][0] += a4.w * w4.x; acc[3][1] += a4.w * w4.y; acc[3][2] += a4.w * w4.z; acc[3][3] += a4.w * w4.w;
        }
        __syncthreads();
    }
#pragma unroll
    for (int i = 0; i < 4; i++) {
        int mm = m0 + tm + i;
        if (mm >= M) break;
        float* crow = C + (size_t)mm * Nn;
#pragma unroll
        for (int j = 0; j < 4; j++) {
            int nn = n0 + tn + j;
            if (nn >= Nn) continue;
            float val = acc[i][j];
            if (GELU) val = gelu_f(val);
            crow[nn] = val;
        }
    }
}

// ---------------- MFMA flash attention: block = (64 q-rows, head, batch), 4 waves ----------------
__global__ __launch_bounds__(256, 2) void attn_mfma(const unsigned short* __restrict__ QKV,
                                                    const unsigned short* __restrict__ Vt,
                                                    unsigned short* __restrict__ O) {
    int qt = blockIdx.x, hh = blockIdx.y, bb = blockIdx.z;
    __shared__ char lds[32768];
    char* Qs = lds;
    char* Ks = lds + 8192;
    char* Vs = lds + 16384;
    char* Ps = lds + 24576;
    int tid = threadIdx.x;
    int w = tid >> 6, l = tid & 63;
    int l15 = l & 15, l16 = l >> 4;

    {
        int r = tid >> 3, g = tid & 7;
        const unsigned short* qbase = QKV + (size_t)(bb * SEQ + qt * QBLK) * 1536 + hh * 64;
#pragma unroll
        for (int i = 0; i < 2; i++) {
            int row = r + i * 32;
            bf16x8 v = *(const bf16x8*)(qbase + (size_t)row * 1536 + g * 8);
            *(bf16x8*)(Qs + row * 128 + ((g * 16) ^ ((row & 7) << 4))) = v;
        }
    }
    f32x4 accO[4];
#pragma unroll
    for (int n = 0; n < 4; n++)
#pragma unroll
        for (int j = 0; j < 4; j++) accO[n][j] = 0.f;
    float m_r[4] = {-1e30f, -1e30f, -1e30f, -1e30f};
    float l_r[4] = {0.f, 0.f, 0.f, 0.f};

    const unsigned short* kbase = QKV + (size_t)(bb * SEQ) * 1536 + 512 + hh * 64;
    const unsigned short* vbase = Vt + (size_t)((bb * NHEAD + hh) * 64) * SEQ;

    for (int kt = 0; kt < SEQ / KBLK; kt++) {
        __syncthreads();
        {
            int r = tid >> 3, g = tid & 7;
#pragma unroll
            for (int i = 0; i < 2; i++) {
                int row = r + i * 32;
                bf16x8 kv = *(const bf16x8*)(kbase + (size_t)(kt * KBLK + row) * 1536 + g * 8);
                *(bf16x8*)(Ks + row * 128 + ((g * 16) ^ ((row & 7) << 4))) = kv;
                bf16x8 vv = *(const bf16x8*)(vbase + (size_t)row * SEQ + kt * KBLK + g * 8);
                *(bf16x8*)(Vs + row * 128 + ((g * 16) ^ ((row & 7) << 4))) = vv;
            }
        }
        __syncthreads();
        f32x4 s_acc[4];
#pragma unroll
        for (int n = 0; n < 4; n++)
#pragma unroll
            for (int j = 0; j < 4; j++) s_acc[n][j] = 0.f;
#pragma unroll
        for (int st = 0; st < 2; st++) {
            int kb = st * 64 + l16 * 16;
            int qrow = w * 16 + l15;
            bf16x8 a = *(const bf16x8*)(Qs + qrow * 128 + (kb ^ ((qrow & 7) << 4)));
#pragma unroll
            for (int n = 0; n < 4; n++) {
                int kr = n * 16 + l15;
                bf16x8 b = *(const bf16x8*)(Ks + kr * 128 + (kb ^ ((kr & 7) << 4)));
                s_acc[n] = __builtin_amdgcn_mfma_f32_16x16x32_bf16(a, b, s_acc[n], 0, 0, 0);
            }
        }
        char* pw = Ps + w * 2048;
#pragma unroll
        for (int j = 0; j < 4; j++) {
            float s0 = s_acc[0][j] * 0.125f, s1 = s_acc[1][j] * 0.125f;
            float s2 = s_acc[2][j] * 0.125f, s3 = s_acc[3][j] * 0.125f;
            float tmax = fmaxf(fmaxf(s0, s1), fmaxf(s2, s3));
#pragma unroll
            for (int o = 1; o < 16; o <<= 1) tmax = fmaxf(tmax, __shfl_xor(tmax, o));
            float mnew = fmaxf(m_r[j], tmax);
            float resc = __expf(m_r[j] - mnew);
            float p0 = __expf(s0 - mnew), p1 = __expf(s1 - mnew);
            float p2 = __expf(s2 - mnew), p3 = __expf(s3 - mnew);
            float ps = p0 + p1 + p2 + p3;
#pragma unroll
            for (int o = 1; o < 16; o <<= 1) ps += __shfl_xor(ps, o);
            l_r[j] = l_r[j] * resc + ps;
            m_r[j] = mnew;
            accO[0][j] *= resc; accO[1][j] *= resc;
            accO[2][j] *= resc; accO[3][j] *= resc;
            int prow = l16 * 4 + j;
            int sw = (prow & 7) << 4;
            *(unsigned short*)(pw + prow * 128 + ((2 * l15) ^ sw)) = f2bf(p0);
            *(unsigned short*)(pw + prow * 128 + ((2 * l15 + 32) ^ sw)) = f2bf(p1);
            *(unsigned short*)(pw + prow * 128 + ((2 * l15 + 64) ^ sw)) = f2bf(p2);
            *(unsigned short*)(pw + prow * 128 + ((2 * l15 + 96) ^ sw)) = f2bf(p3);
        }
#pragma unroll
        for (int st = 0; st < 2; st++) {
            int kb = st * 64 + l16 * 16;
            bf16x8 pa = *(const bf16x8*)(pw + l15 * 128 + (kb ^ ((l15 & 7) << 4)));
#pragma unroll
            for (int n = 0; n < 4; n++) {
                int vr = n * 16 + l15;
                bf16x8 vb = *(const bf16x8*)(Vs + vr * 128 + (kb ^ ((vr & 7) << 4)));
                accO[n] = __builtin_amdgcn_mfma_f32_16x16x32_bf16(pa, vb, accO[n], 0, 0, 0);
            }
        }
    }
    unsigned short* obase = O + (size_t)(bb * SEQ + qt * QBLK + w * 16) * DMODEL + hh * 64;
#pragma unroll
    for (int j = 0; j < 4; j++) {
        float inv = 1.f / l_r[j];
        int row = l16 * 4 + j;
#pragma unroll
        for (int n = 0; n < 4; n++)
            obase[(size_t)row * DMODEL + n * 16 + l15] = f2bf(accO[n][j] * inv);
    }
}

// ---------------- router: shuffle-reduced stats ----------------
__global__ __launch_bounds__(256) void router_topk(const float* __restrict__ rsc,
                                                   float* __restrict__ topw,
                                                   int* __restrict__ topi,
                                                   int* __restrict__ cnt,
                                                   float* __restrict__ sumP,
                                                   float* __restrict__ zacc) {
    __shared__ float wP[4][NEXP];
    __shared__ int wC[4][NEXP];
    __shared__ float wZ[4];
    int tid = threadIdx.x;
    int wv = tid >> 6, lane = tid & 63;
    int n = blockIdx.x * 256 + tid;
    float sc[NEXP];
    float mx = -1e30f;
#pragma unroll
    for (int e = 0; e < NEXP; e++) { sc[e] = rsc[n * NEXP + e]; mx = fmaxf(mx, sc[e]); }
    float se = 0.f;
#pragma unroll
    for (int e = 0; e < NEXP; e++) { sc[e] = expf(sc[e] - mx); se += sc[e]; }
    float invse = 1.f / se;
    float lse = mx + logf(se);
    float z = lse * lse;
#pragma unroll
    for (int o = 32; o; o >>= 1) z += __shfl_xor(z, o);
    if (lane == 0) wZ[wv] = z;
#pragma unroll
    for (int e = 0; e < NEXP; e++) {
        float pv = sc[e] * invse;
#pragma unroll
        for (int o = 32; o; o >>= 1) pv += __shfl_xor(pv, o);
        if (lane == 0) wP[wv][e] = pv;
    }
    float tv[TOPK]; int ti[TOPK];
#pragma unroll
    for (int k = 0; k < TOPK; k++) {
        float best = -1.f; int bi = 0;
#pragma unroll
        for (int e = 0; e < NEXP; e++) {
            if (sc[e] > best) { best = sc[e]; bi = e; }
        }
        tv[k] = best * invse; ti[k] = bi; sc[bi] = -1.f;
    }
    float s4 = tv[0] + tv[1] + tv[2] + tv[3];
#pragma unroll
    for (int k = 0; k < TOPK; k++) {
        topw[n * TOPK + k] = tv[k] / s4;
        topi[n * TOPK + k] = ti[k];
    }
#pragma unroll
    for (int e = 0; e < NEXP; e++) {
        unsigned long long b0 = __ballot(ti[0] == e);
        unsigned long long b1 = __ballot(ti[1] == e);
        unsigned long long b2 = __ballot(ti[2] == e);
        unsigned long long b3 = __ballot(ti[3] == e);
        if (lane == 0)
            wC[wv][e] = __popcll(b0) + __popcll(b1) + __popcll(b2) + __popcll(b3);
    }
    __syncthreads();
    if (tid < NEXP) {
        atomicAdd(&sumP[tid], wP[0][tid] + wP[1][tid] + wP[2][tid] + wP[3][tid]);
        atomicAdd(&cnt[tid], wC[0][tid] + wC[1][tid] + wC[2][tid] + wC[3][tid]);
    }
    if (tid == 0) atomicAdd(zacc, wZ[0] + wZ[1] + wZ[2] + wZ[3]);
}

// ---------------- scan (1 wave, shuffle prefix): padded offsets + tile map + aux ----------------
__global__ void scanaux_kernel(const int* __restrict__ cnt, int* __restrict__ poff,
                               int* __restrict__ tinfo,
                               const float* __restrict__ sumP, const float* __restrict__ zacc,
                               float* __restrict__ out_aux, int l) {
    int lane = threadIdx.x;
    int c = (lane < NEXP) ? cnt[lane] : 0;
    int nt = (c + 127) >> 7;
    int x = nt;
#pragma unroll
    for (int o = 1; o < 32; o <<= 1) {
        int y = __shfl_up(x, o);
        if (lane >= o) x += y;
    }
    int excl = x - nt;
    if (lane < NEXP) {
        poff[lane] = excl * 128;
        for (int i = 0; i < nt; i++) {
            tinfo[1 + 2 * (excl + i)] = lane;
            tinfo[2 + 2 * (excl + i)] = i * 128;
        }
    }
    float lb = (lane < NEXP) ? ((float)c / (float)NTOK) * (sumP[lane] / (float)NTOK) : 0.f;
#pragma unroll
    for (int o = 32; o; o >>= 1) lb += __shfl_xor(lb, o);
    if (lane == 31) {
        tinfo[0] = x;
        out_aux[l] = lb * (float)NEXP / (float)TOPK;
        out_aux[NLAYER + l] = zacc[0] / (float)NTOK;
    }
}

// ---------------- scatter: LDS-aggregated per-block bases ----------------
__global__ __launch_bounds__(256) void scatter_kernel(const int* __restrict__ topi,
                                                      const int* __restrict__ poff,
                                                      int* __restrict__ cursor,
                                                      int* __restrict__ perm,
                                                      int* __restrict__ pos) {
    __shared__ int lcnt[NEXP];
    __shared__ int lbase[NEXP];
    if (threadIdx.x < NEXP) lcnt[threadIdx.x] = 0;
    __syncthreads();
    int i = blockIdx.x * 256 + threadIdx.x;
    int e = topi[i];
    int lr = atomicAdd(&lcnt[e], 1);
    __syncthreads();
    if (threadIdx.x < NEXP && lcnt[threadIdx.x] > 0)
        lbase[threadIdx.x] = atomicAdd(&cursor[threadIdx.x], lcnt[threadIdx.x]);
    __syncthreads();
    int g = poff[e] + lbase[e] + lr;
    perm[g] = i >> 2;
    pos[i] = g;
}

// ---------------- launcher ----------------
extern "C" void kernel_launch(void* const* d_in, const int* in_sizes, int n_in,
                              void* d_out, int out_size, void* d_ws, size_t ws_size,
                              hipStream_t stream) {
    (void)in_sizes; (void)n_in; (void)out_size; (void)ws_size;
    const float* x_in  = (const float*)d_in[0];
    const float* ln1_s = (const float*)d_in[1];
    const float* ln1_b = (const float*)d_in[2];
    const float* ln2_s = (const float*)d_in[3];
    const float* ln2_b = (const float*)d_in[4];
    const float* wq = (const float*)d_in[5];
    const float* bq = (const float*)d_in[6];
    const float* wk = (const float*)d_in[7];
    const float* bk = (const float*)d_in[8];
    const float* wv = (const float*)d_in[9];
    const float* bv = (const float*)d_in[10];
    const float* wo = (const float*)d_in[11];
    const float* bo = (const float*)d_in[12];
    const float* rdw = (const float*)d_in[13];
    const float* ruw = (const float*)d_in[14];
    const float* w1 = (const float*)d_in[15];
    const float* b1 = (const float*)d_in[16];
    const float* w2 = (const float*)d_in[17];
    const float* b2 = (const float*)d_in[18];
    const float* ws1 = (const float*)d_in[19];
    const float* bs1 = (const float*)d_in[20];
    const float* ws2 = (const float*)d_in[21];
    const float* bs2 = (const float*)d_in[22];
    const float* fn_s = (const float*)d_in[23];
    const float* fn_b = (const float*)d_in[24];

    float* ws = (float*)d_ws;
    const size_t ND = (size_t)NTOK * DMODEL;
    const size_t PADROWS = (size_t)MAXTILE * 128;
    size_t o = 0;
    float* xb  = ws + o; o += ND;
    float* h   = ws + o; o += ND;
    unsigned short* hb     = (unsigned short*)(ws + o); o += ND / 2;
    unsigned short* qkv_bf = (unsigned short*)(ws + o); o += (size_t)NTOK * 1536 / 2;
    unsigned short* vT     = (unsigned short*)(ws + o); o += ND / 2;
    unsigned short* t1b    = (unsigned short*)(ws + o); o += ND / 2;
    unsigned short* hidb   = (unsigned short*)(ws + o); o += (size_t)NTOK * HSHARED / 2;
    unsigned short* eogb   = (unsigned short*)(ws + o); o += PADROWS * DMODEL / 2;
    float* pbuf = ws + o; o += 4 * ND;                 // split-K partials (max SK=4)
    float* rdru = ws + o; o += (size_t)DMODEL * NEXP;
    float* rsc  = ws + o; o += (size_t)NTOK * NEXP;
    float* topw = ws + o; o += (size_t)NTOK * TOPK;
    float* bqkv = ws + o; o += 1536;
    int* topi = (int*)(ws + o); o += (size_t)NTOK * TOPK;
    int* pos  = (int*)(ws + o); o += (size_t)NTOK * TOPK;
    int* perm = (int*)(ws + o); o += PADROWS;
    int* stats = (int*)(ws + o); o += 256;
    int* tinfo = (int*)(ws + o); o += 512;
    int* cnt = stats;
    int* cursor = stats + 32;
    int* poff = stats + 64;
    float* sumP = (float*)(stats + 96);
    float* zacc = sumP + 32;
    unsigned short* wbf = (unsigned short*)(ws + o);
    const size_t DDu = (size_t)DMODEL * DMODEL;
    unsigned short* wqkvt = wbf;
    unsigned short* wot  = wqkvt + 3 * DDu;
    unsigned short* w1t  = wot + DDu;
    unsigned short* w2t  = w1t + (size_t)NEXP * DDu;
    unsigned short* ws1t = w2t + (size_t)NEXP * DDu;
    unsigned short* ws2t = ws1t + (size_t)DMODEL * HSHARED;

    float* out_x = (float*)d_out;
    float* out_aux = out_x + ND;

    hipMemcpyAsync(xb, x_in, ND * sizeof(float), hipMemcpyDeviceToDevice, stream);

    dim3 blk(256);
    dim3 gQKV(1536 / 64, NTOK / 128);           // 768 blocks (3/CU)
    dim3 gOP(DMODEL / 64, NTOK / 128, 2);       // 512 blocks
    dim3 gF2(DMODEL / 64, NTOK / 128, 4);       // 1024 blocks
    dim3 gHS(HSHARED / 64, NTOK / 128);         // 2048 blocks
    dim3 gE1(HEXP / 64, MAXTILE);               // 1280 blocks (5/CU)
    dim3 gE2(DMODEL / 64, MAXTILE);

    for (int l = 0; l < NLAYER; l++) {
        const size_t DD = (size_t)DMODEL * DMODEL;
        // ---- weight transpose+convert ----
        wt_kernel<<<dim3(8, 8, 1), blk, 0, stream>>>(wq + l * DD, wqkvt, DMODEL, DMODEL);
        wt_kernel<<<dim3(8, 8, 1), blk, 0, stream>>>(wk + l * DD, wqkvt + DDu, DMODEL, DMODEL);
        wt_kernel<<<dim3(8, 8, 1), blk, 0, stream>>>(wv + l * DD, wqkvt + 2 * DDu, DMODEL, DMODEL);
        wt_kernel<<<dim3(8, 8, 1), blk, 0, stream>>>(wo + l * DD, wot, DMODEL, DMODEL);
        wt_kernel<<<dim3(8, 8, NEXP), blk, 0, stream>>>(w1 + (size_t)l * NEXP * DD, w1t, DMODEL, HEXP);
        wt_kernel<<<dim3(8, 8, NEXP), blk, 0, stream>>>(w2 + (size_t)l * NEXP * DD, w2t, HEXP, DMODEL);
        wt_kernel<<<dim3(HSHARED / 64, 8, 1), blk, 0, stream>>>(ws1 + (size_t)l * DMODEL * HSHARED, ws1t, DMODEL, HSHARED);
        wt_kernel<<<dim3(8, HSHARED / 64, 1), blk, 0, stream>>>(ws2 + (size_t)l * HSHARED * DMODEL, ws2t, HSHARED, DMODEL);
        biaspack<<<6, blk, 0, stream>>>(bq + l * DMODEL, bk + l * DMODEL, bv + l * DMODEL, bqkv);
        // ---- router weight fold: rdru = rd @ ru ----
        gemm_tile<false><<<dim3(1, 8), blk, 0, stream>>>(
            rdw + (size_t)l * DMODEL * RRANK, ruw + (size_t)l * RRANK * NEXP, rdru, DMODEL, NEXP, RRANK, RRANK);

        // ---- LN1 (bf16 out only) ----
        ln_kernel<1><<<NTOK / 4, blk, 0, stream>>>(xb, ln1_s + l * DMODEL, ln1_b + l * DMODEL, nullptr, hb);
        // ---- fused QKV (BK=128) ----
        gemm_mfma<false, false, false, false, true, 1, 128><<<gQKV, blk, 0, stream>>>(
            hb, wqkvt, bqkv, nullptr, qkv_bf, NTOK, 1536, DMODEL, nullptr, nullptr, nullptr, nullptr);
        // ---- V transpose ----
        vtr_kernel<<<dim3(SEQ / 64, NHEAD, BATCH), blk, 0, stream>>>(qkv_bf, vT);
        // ---- MFMA attention ----
        attn_mfma<<<dim3(SEQ / QBLK, NHEAD, BATCH), blk, 0, stream>>>(qkv_bf, vT, t1b);
        // ---- out proj: split-K=2 (BK=128) + reduce ----
        gemm_mfma<false, false, false, false, false, 2, 128><<<gOP, blk, 0, stream>>>(
            t1b, wot, nullptr, nullptr, pbuf, NTOK, DMODEL, DMODEL, nullptr, nullptr, nullptr, nullptr);
        reduce_kernel<2, false><<<ND / 1024, blk, 0, stream>>>(
            pbuf, bo + l * DMODEL, nullptr, nullptr, nullptr, xb);
        // ---- LN2 ----
        ln_kernel<2><<<NTOK / 4, blk, 0, stream>>>(xb, ln2_s + l * DMODEL, ln2_b + l * DMODEL, h, hb);
        // ---- router ----
        hipMemsetAsync(stats, 0, 640, stream);
        hipMemsetAsync(perm, 0, PADROWS * sizeof(int), stream);   // pad rows -> token 0 (outputs discarded)
        gemm_tile<false><<<dim3(1, NTOK / 64), blk, 0, stream>>>(
            h, rdru, rsc, NTOK, NEXP, DMODEL, DMODEL);
        router_topk<<<NTOK / 256, blk, 0, stream>>>(rsc, topw, topi, cnt, sumP, zacc);
        scanaux_kernel<<<1, 64, 0, stream>>>(cnt, poff, tinfo, sumP, zacc, out_aux, l);
        scatter_kernel<<<NTOK * TOPK / 256, blk, 0, stream>>>(topi, poff, cursor, perm, pos);
        // ---- expert FFN (BK=64: keep gather-path occupancy) ----
        gemm_mfma<true, false, true, true, true><<<gE1, blk, 0, stream>>>(
            hb, w1t, b1 + (size_t)l * NEXP * HEXP, nullptr,
            hidb, 0, HEXP, DMODEL, perm, cnt, poff, tinfo);
        gemm_mfma<false, false, false, true, true><<<gE2, blk, 0, stream>>>(
            hidb, w2t, b2 + (size_t)l * NEXP * DMODEL, nullptr,
            eogb, 0, DMODEL, HEXP, nullptr, cnt, poff, tinfo);
        // ---- shared FFN1 (BK=128) ----
        gemm_mfma<true, false, false, false, true, 1, 128><<<gHS, blk, 0, stream>>>(
            hb, ws1t, bs1 + (size_t)l * HSHARED, nullptr,
            hidb, NTOK, HSHARED, DMODEL, nullptr, nullptr, nullptr, nullptr);
        // ---- shared FFN2: split-K=4 (BK=128) + fused reduce ----
        gemm_mfma<false, false, false, false, false, 4, 128><<<gF2, blk, 0, stream>>>(
            hidb, ws2t, nullptr, nullptr, pbuf, NTOK, DMODEL, HSHARED, nullptr, nullptr, nullptr, nullptr);
        reduce_kernel<4, true><<<ND / 1024, blk, 0, stream>>>(
            pbuf, bs2 + l * DMODEL, eogb, topw, pos, xb);
    }
    ln_kernel<0><<<NTOK / 4, blk, 0, stream>>>(xb, fn_s, fn_b, out_x, nullptr);
}

// Round 14
// 609.507 us; speedup vs baseline: 1.0615x; 1.0615x over previous
//
#include <hip/hip_runtime.h>
#include <math.h>

// ---- problem constants ----
#define NTOK    4096      // B*S
#define DMODEL  512
#define NEXP    32
#define RRANK   64
#define HEXP    512
#define HSHARED 4096
#define SEQ     1024
#define BATCH   4
#define NHEAD   8
#define TOPK    4
#define NLAYER  2
#define QBLK    64
#define KBLK    64
#define MAXTILE 160       // max padded expert m-tiles: 16384/128 + 32

typedef __attribute__((ext_vector_type(8))) short bf16x8;
typedef __attribute__((ext_vector_type(4))) float f32x4;

__device__ __forceinline__ float gelu_f(float x) {
    float t = tanhf(0.7978845608028654f * (x + 0.044715f * x * x * x));
    return 0.5f * x * (1.f + t);
}
__device__ __forceinline__ unsigned short f2bf(float f) {
    unsigned int u = __float_as_uint(f);
    u += 0x7FFFu + ((u >> 16) & 1u);
    return (unsigned short)(u >> 16);
}
__device__ __forceinline__ float bf2f(unsigned short u) {
    return __uint_as_float((unsigned int)u << 16);
}
// async global->LDS, 16B per lane; LDS dest wave-uniform base + lane*16
__device__ __forceinline__ void gl_lds16(const void* g, void* l) {
    __builtin_amdgcn_global_load_lds(
        (const __attribute__((address_space(1))) void*)g,
        (__attribute__((address_space(3))) void*)l, 16, 0, 0);
}

// ---------------- LayerNorm: one wave per row of 512; MODE 0=f32, 1=bf16, 2=both ----------------
template <int MODE>
__global__ __launch_bounds__(256) void ln_kernel(const float* __restrict__ x,
                                                 const float* __restrict__ s,
                                                 const float* __restrict__ b,
                                                 float* __restrict__ outf,
                                                 unsigned short* __restrict__ outb) {
    int wave = threadIdx.x >> 6, lane = threadIdx.x & 63;
    int row = blockIdx.x * 4 + wave;
    const float* xr = x + (size_t)row * DMODEL;
    float v[8];
    float sum = 0.f;
#pragma unroll
    for (int i = 0; i < 8; i++) { v[i] = xr[lane + i * 64]; sum += v[i]; }
#pragma unroll
    for (int o = 32; o; o >>= 1) sum += __shfl_xor(sum, o);
    float m = sum * (1.f / DMODEL);
    float vs = 0.f;
#pragma unroll
    for (int i = 0; i < 8; i++) { float d = v[i] - m; vs += d * d; }
#pragma unroll
    for (int o = 32; o; o >>= 1) vs += __shfl_xor(vs, o);
    float rstd = rsqrtf(vs * (1.f / DMODEL) + 1e-5f);
#pragma unroll
    for (int i = 0; i < 8; i++) {
        int c = lane + i * 64;
        float r = (v[i] - m) * rstd * s[c] + b[c];
        if (MODE != 1) outf[(size_t)row * DMODEL + c] = r;
        if (MODE != 0) outb[(size_t)row * DMODEL + c] = f2bf(r);
    }
}

// ---------------- fused split-K reduce (+bias +residual +MoE) + LayerNorm ----------------
// One wave per row (lane covers 8 consecutive cols -> vectorized loads).
// Updates xb in place, then LN(xb_row) with scale s / bias b:
// MODE 0 -> outf only, 1 -> outb only, 2 -> both.
template <int SK, bool MOE, int MODE>
__global__ __launch_bounds__(256) void reduceln_kernel(
    const float* __restrict__ pbuf, const float* __restrict__ bias,
    const unsigned short* __restrict__ eogb, const float* __restrict__ topw,
    const int* __restrict__ pos, float* __restrict__ xb,
    const float* __restrict__ s, const float* __restrict__ b,
    float* __restrict__ outf, unsigned short* __restrict__ outb) {
    int wave = threadIdx.x >> 6, lane = threadIdx.x & 63;
    int row = blockIdx.x * 4 + wave;
    int cb = lane * 8;
    size_t base = (size_t)row * DMODEL + cb;
    float v[8];
    {
        float4 a0 = *(const float4*)(xb + base);
        float4 a1 = *(const float4*)(xb + base + 4);
        float4 b0 = *(const float4*)(bias + cb);
        float4 b1 = *(const float4*)(bias + cb + 4);
        v[0] = a0.x + b0.x; v[1] = a0.y + b0.y; v[2] = a0.z + b0.z; v[3] = a0.w + b0.w;
        v[4] = a1.x + b1.x; v[5] = a1.y + b1.y; v[6] = a1.z + b1.z; v[7] = a1.w + b1.w;
    }
#pragma unroll
    for (int sk = 0; sk < SK; sk++) {
        const float* p = pbuf + (size_t)sk * NTOK * DMODEL + base;
        float4 p0 = *(const float4*)p;
        float4 p1 = *(const float4*)(p + 4);
        v[0] += p0.x; v[1] += p0.y; v[2] += p0.z; v[3] += p0.w;
        v[4] += p1.x; v[5] += p1.y; v[6] += p1.z; v[7] += p1.w;
    }
    if (MOE) {
#pragma unroll
        for (int k = 0; k < TOPK; k++) {
            float w = topw[row * TOPK + k];
            bf16x8 e = *(const bf16x8*)(eogb + (size_t)pos[row * TOPK + k] * DMODEL + cb);
#pragma unroll
            for (int i = 0; i < 8; i++) v[i] += w * bf2f((unsigned short)e[i]);
        }
    }
    // write updated residual stream
    *(float4*)(xb + base) = make_float4(v[0], v[1], v[2], v[3]);
    *(float4*)(xb + base + 4) = make_float4(v[4], v[5], v[6], v[7]);
    // LayerNorm over the row
    float sum = 0.f;
#pragma unroll
    for (int i = 0; i < 8; i++) sum += v[i];
#pragma unroll
    for (int o = 32; o; o >>= 1) sum += __shfl_xor(sum, o);
    float m = sum * (1.f / DMODEL);
    float vs = 0.f;
#pragma unroll
    for (int i = 0; i < 8; i++) { float d = v[i] - m; vs += d * d; }
#pragma unroll
    for (int o = 32; o; o >>= 1) vs += __shfl_xor(vs, o);
    float rstd = rsqrtf(vs * (1.f / DMODEL) + 1e-5f);
#pragma unroll
    for (int i = 0; i < 8; i++) {
        int c = cb + i;
        float r = (v[i] - m) * rstd * s[c] + b[c];
        if (MODE != 1) outf[(size_t)row * DMODEL + c] = r;
        if (MODE != 0) outb[(size_t)row * DMODEL + c] = f2bf(r);
    }
}

// ---------------- weight transpose + fp32->bf16: src [K][N] -> dst [N][K] bf16 ----------------
__global__ __launch_bounds__(256) void wt_kernel(const float* __restrict__ src,
                                                 unsigned short* __restrict__ dst,
                                                 int K, int N) {
    src += (size_t)blockIdx.z * K * N;
    dst += (size_t)blockIdx.z * K * N;
    __shared__ float t[64][68];
    int k0 = blockIdx.y * 64, n0 = blockIdx.x * 64;
    int tid = threadIdx.x;
    int r = tid >> 2;
    int cb = (tid & 3) * 4;
#pragma unroll
    for (int i = 0; i < 4; i++)
        *(float4*)&t[r][cb + i * 16] = *(const float4*)(src + (size_t)(k0 + r) * N + n0 + cb + i * 16);
    __syncthreads();
    int g = tid & 7;
    int nr = tid >> 3;
#pragma unroll
    for (int i = 0; i < 2; i++) {
        int n = nr + i * 32;
        bf16x8 v;
#pragma unroll
        for (int j = 0; j < 8; j++) v[j] = (short)f2bf(t[g * 8 + j][n]);
        *(bf16x8*)(dst + (size_t)(n0 + n) * K + k0 + g * 8) = v;
    }
}

// ---------------- bias pack + stats zero: [bq|bk|bv] -> bqkv[1536]; zero cnt/cursor/poff/sumP/zacc ----------------
__global__ __launch_bounds__(256) void biaspack(const float* __restrict__ a,
                                                const float* __restrict__ b,
                                                const float* __restrict__ c,
                                                float* __restrict__ dst,
                                                int* __restrict__ stats) {
    int i = blockIdx.x * 256 + threadIdx.x;
    float v = (i < 512) ? a[i] : (i < 1024 ? b[i - 512] : c[i - 1024]);
    dst[i] = v;
    if (i < 160) stats[i] = 0;
}

// ---------------- V transpose: qkv[.,1024+h*64+d] -> Vt[b,h,d,s] (bf16) ----------------
__global__ __launch_bounds__(256) void vtr_kernel(const unsigned short* __restrict__ QKV,
                                                  unsigned short* __restrict__ Vt) {
    int st = blockIdx.x, hh = blockIdx.y, bb = blockIdx.z;
    __shared__ unsigned short t[64][72];
    int r = threadIdx.x >> 3, g = threadIdx.x & 7;
#pragma unroll
    for (int i = 0; i < 2; i++) {
        int row = r + i * 32;
        bf16x8 v = *(const bf16x8*)(QKV + (size_t)(bb * SEQ + st * 64 + row) * 1536 + 1024 + hh * 64 + g * 8);
        *(bf16x8*)&t[row][g * 8] = v;
    }
    __syncthreads();
#pragma unroll
    for (int i = 0; i < 2; i++) {
        int d = r + i * 32;
        bf16x8 v;
#pragma unroll
        for (int j = 0; j < 8; j++) v[j] = (short)t[g * 8 + j][d];
        *(bf16x8*)(Vt + (size_t)((bb * NHEAD + hh) * 64 + d) * SEQ + st * 64 + g * 8) = v;
    }
}

// ---------------- bf16 MFMA GEMM: 128x64 tile, BK=64 (R12 proven config) ----------------
// 4 waves in 2m x 2n, each computes 64x32 (4x2 frags). LDS 24KB -> 3-6 blocks/CU.
// XCD-aware bijective block swizzle + hoisted k-independent row pointers.
template <bool GELU, bool DORES, bool GATHER, bool EXPERT, bool OUTBF16, int SK = 1, int BK = 64>
__global__ __launch_bounds__(256, 2) void gemm_mfma(
    const unsigned short* __restrict__ Ab, const unsigned short* __restrict__ Wt,
    const float* __restrict__ bias, const float* __restrict__ res,
    void* __restrict__ Cvoid, int M, int Nn, int Kk,
    const int* __restrict__ rowmap, const int* __restrict__ cntp,
    const int* __restrict__ offp, const int* __restrict__ tinfo) {
    constexpr int RS  = BK * 2;        // row stride bytes
    constexpr int CH  = RS / 16;       // 16B chunks per row
    constexpr int RPI = 1024 / RS;     // rows per gl_lds issue
    constexpr int AIW = 32 / RPI;      // A issues per wave
    constexpr int BIW = 16 / RPI;      // B issues per wave
    unsigned int bid = blockIdx.y * gridDim.x + blockIdx.x;
    unsigned int tot = gridDim.x * gridDim.y;
    unsigned int lg = (bid & 7) * (tot >> 3) + (bid >> 3);
    unsigned int bx = lg % gridDim.x;
    unsigned int by = lg / gridDim.x;
    int n0 = bx * 64;
    int m0;
    size_t cbase = 0;
    int kbeg = 0, kend = Kk;
    if (EXPERT) {
        int t = by;
        if (t >= tinfo[0]) return;
        int e = tinfo[1 + 2 * t];
        m0 = tinfo[2 + 2 * t];
        M = cntp[e];
        Wt += (size_t)e * Nn * Kk;
        bias += (size_t)e * Nn;
        int oe = offp[e];
        cbase = (size_t)oe * Nn;
        if (GATHER) rowmap += oe;
        else Ab += (size_t)oe * Kk;
    } else {
        m0 = by * 128;
    }
    if (SK > 1) {
        int s = blockIdx.z;
        int chunk = Kk / SK;
        kbeg = s * chunk;
        kend = kbeg + chunk;
        cbase = (size_t)s * M * Nn;
    }
    __shared__ short As[128 * BK];
    __shared__ short Bs[64 * BK];
    char* asb = (char*)As;
    char* bsb = (char*)Bs;
    int tid = threadIdx.x;
    int wave = tid >> 6, lane = tid & 63;
    int wm = wave >> 1, wn = wave & 1;
    int l15 = lane & 15, l16 = lane >> 4;
    int c16 = lane & (CH - 1);
    int ro  = lane / CH;

    const char* aptr[AIW];
    const char* bptr[BIW];
#pragma unroll
    for (int j = 0; j < AIW; j++) {
        int rloc = j * RPI + ro;
        int row = wave * 32 + rloc;
        int grow = m0 + row;
        int arow = GATHER ? rowmap[grow] : grow;   // pad rows: rowmap=0 (zeroed), output discarded
        int srcoff = ((c16 ^ (rloc & (CH - 1))) << 4);
        aptr[j] = (const char*)Ab + (((size_t)arow * Kk) << 1) + srcoff;
    }
#pragma unroll
    for (int j = 0; j < BIW; j++) {
        int rloc = j * RPI + ro;
        int row = wave * 16 + rloc;
        int srcoff = ((c16 ^ (rloc & (CH - 1))) << 4);
        bptr[j] = (const char*)Wt + (((size_t)(n0 + row) * Kk) << 1) + srcoff;
    }

    f32x4 acc[4][2];
#pragma unroll
    for (int m = 0; m < 4; m++)
#pragma unroll
        for (int n = 0; n < 2; n++)
#pragma unroll
            for (int j = 0; j < 4; j++) acc[m][n][j] = 0.f;

    for (int k0 = kbeg; k0 < kend; k0 += BK) {
        size_t kb = (size_t)k0 << 1;
#pragma unroll
        for (int j = 0; j < AIW; j++) gl_lds16(aptr[j] + kb, asb + wave * 32 * RS + j * 1024);
#pragma unroll
        for (int j = 0; j < BIW; j++) gl_lds16(bptr[j] + kb, bsb + wave * 16 * RS + j * 1024);
        __syncthreads();
#pragma unroll
        for (int kk = 0; kk < BK / 32; kk++) {
            int k8 = kk * 4 + l16;
            bf16x8 a[4], b[2];
#pragma unroll
            for (int m = 0; m < 4; m++) {
                int row = wm * 64 + m * 16 + l15;
                a[m] = *(const bf16x8*)(asb + row * RS + ((k8 * 16) ^ ((row & (CH - 1)) << 4)));
            }
#pragma unroll
            for (int n = 0; n < 2; n++) {
                int row = wn * 32 + n * 16 + l15;
                b[n] = *(const bf16x8*)(bsb + row * RS + ((k8 * 16) ^ ((row & (CH - 1)) << 4)));
            }
#pragma unroll
            for (int m = 0; m < 4; m++)
#pragma unroll
                for (int n = 0; n < 2; n++)
                    acc[m][n] = __builtin_amdgcn_mfma_f32_16x16x32_bf16(a[m], b[n], acc[m][n], 0, 0, 0);
        }
        __syncthreads();
    }

#pragma unroll
    for (int m = 0; m < 4; m++) {
#pragma unroll
        for (int n = 0; n < 2; n++) {
            int col = n0 + wn * 32 + n * 16 + l15;
            float bv = (SK == 1 && bias) ? bias[col] : 0.f;
#pragma unroll
            for (int j = 0; j < 4; j++) {
                int row = m0 + wm * 64 + m * 16 + l16 * 4 + j;
                if (row >= M) continue;
                float val = acc[m][n][j] + bv;
                if (SK == 1 && GELU) val = gelu_f(val);
                if (SK == 1 && DORES) val += res[(size_t)row * Nn + col];
                if (SK == 1 && OUTBF16)
                    ((unsigned short*)Cvoid)[cbase + (size_t)row * Nn + col] = f2bf(val);
                else
                    ((float*)Cvoid)[cbase + (size_t)row * Nn + col] = val;
            }
        }
    }
}

// ---------------- small fp32 GEMM (router only) ----------------
template <bool GELU>
__global__ __launch_bounds__(256) void gemm_tile(
    const float* __restrict__ A, const float* __restrict__ W,
    float* __restrict__ C, int M, int Nn, int Kk, int lda) {
    int n0 = blockIdx.x * 64;
    int m0 = blockIdx.y * 64;
    __shared__ float Asf[16][68];
    __shared__ float Wsf[16][68];
    int tid = threadIdx.x;
    int ml = tid >> 2, kl = (tid & 3) << 2;
    bool avalid = (m0 + ml) < M;
    int arow = m0 + ml;
    const float* aptr = A + (size_t)arow * lda + kl;
    int kr = tid >> 4, nc = (tid & 15) << 2;
    bool wvalid = (n0 + nc) < Nn;
    const float* wptr = W + (size_t)kr * Nn + n0 + nc;
    int tm = (tid >> 4) << 2, tn = (tid & 15) << 2;
    float acc[4][4] = {{0.f}};
    for (int k0 = 0; k0 < Kk; k0 += 16) {
        float4 av = make_float4(0.f, 0.f, 0.f, 0.f);
        float4 wv = make_float4(0.f, 0.f, 0.f, 0.f);
        if (avalid) av = *(const float4*)(aptr + k0);
        if (wvalid) wv = *(const float4*)(wptr + (size_t)k0 * Nn);
        Asf[kl + 0][ml] = av.x; Asf[kl + 1][ml] = av.y;
        Asf[kl + 2][ml] = av.z; Asf[kl + 3][ml] = av.w;
        *(float4*)&Wsf[kr][nc] = wv;
        __syncthreads();
#pragma unroll
        for (int kk = 0; kk < 16; kk++) {
            float4 a4 = *(const float4*)&Asf[kk][tm];
            float4 w4 = *(const float4*)&Wsf[kk][tn];
            acc[0][0] += a4.x * w4.x; acc[0][1] += a4.x * w4.y; acc[0][2] += a4.x * w4.z; acc[0][3] += a4.x * w4.w;
            acc[1][0] += a4.y * w4.x; acc[1][1] += a4.y * w4.y; acc[1][2] += a4.y * w4.z; acc[1][3] += a4.y * w4.w;
            acc[2][0] += a4.z * w4.x; acc[2][1] += a4.z * w4.y; acc[2][2] += a4.z * w4.z; acc[2][3] += a4.z * w4.w;
            acc[3][0] += a4.w * w4.x; acc[3][1] += a4.w * w4.y; acc[3][2] += a4.w * w4.z; acc[3][3] += a4.w * w4.w;
        }
        __syncthreads();
    }
#pragma unroll
    for (int i = 0; i < 4; i++) {
        int mm = m0 + tm + i;
        if (mm >= M) break;
        float* crow = C + (size_t)mm * Nn;
#pragma unroll
        for (int j = 0; j < 4; j++) {
            int nn = n0 + tn + j;
            if (nn >= Nn) continue;
            float val = acc[i][j];
            if (GELU) val = gelu_f(val);
            crow[nn] = val;
        }
    }
}

// ---------------- MFMA flash attention: block = (64 q-rows, head, batch), 4 waves ----------------
__global__ __launch_bounds__(256, 2) void attn_mfma(const unsigned short* __restrict__ QKV,
                                                    const unsigned short* __restrict__ Vt,
                                                    unsigned short* __restrict__ O) {
    int qt = blockIdx.x, hh = blockIdx.y, bb = blockIdx.z;
    __shared__ char lds[32768];
    char* Qs = lds;
    char* Ks = lds + 8192;
    char* Vs = lds + 16384;
    char* Ps = lds + 24576;
    int tid = threadIdx.x;
    int w = tid >> 6, l = tid & 63;
    int l15 = l & 15, l16 = l >> 4;

    {
        int r = tid >> 3, g = tid & 7;
        const unsigned short* qbase = QKV + (size_t)(bb * SEQ + qt * QBLK) * 1536 + hh * 64;
#pragma unroll
        for (int i = 0; i < 2; i++) {
            int row = r + i * 32;
            bf16x8 v = *(const bf16x8*)(qbase + (size_t)row * 1536 + g * 8);
            *(bf16x8*)(Qs + row * 128 + ((g * 16) ^ ((row & 7) << 4))) = v;
        }
    }
    f32x4 accO[4];
#pragma unroll
    for (int n = 0; n < 4; n++)
#pragma unroll
        for (int j = 0; j < 4; j++) accO[n][j] = 0.f;
    float m_r[4] = {-1e30f, -1e30f, -1e30f, -1e30f};
    float l_r[4] = {0.f, 0.f, 0.f, 0.f};

    const unsigned short* kbase = QKV + (size_t)(bb * SEQ) * 1536 + 512 + hh * 64;
    const unsigned short* vbase = Vt + (size_t)((bb * NHEAD + hh) * 64) * SEQ;

    for (int kt = 0; kt < SEQ / KBLK; kt++) {
        __syncthreads();
        {
            int r = tid >> 3, g = tid & 7;
#pragma unroll
            for (int i = 0; i < 2; i++) {
                int row = r + i * 32;
                bf16x8 kv = *(const bf16x8*)(kbase + (size_t)(kt * KBLK + row) * 1536 + g * 8);
                *(bf16x8*)(Ks + row * 128 + ((g * 16) ^ ((row & 7) << 4))) = kv;
                bf16x8 vv = *(const bf16x8*)(vbase + (size_t)row * SEQ + kt * KBLK + g * 8);
                *(bf16x8*)(Vs + row * 128 + ((g * 16) ^ ((row & 7) << 4))) = vv;
            }
        }
        __syncthreads();
        f32x4 s_acc[4];
#pragma unroll
        for (int n = 0; n < 4; n++)
#pragma unroll
            for (int j = 0; j < 4; j++) s_acc[n][j] = 0.f;
#pragma unroll
        for (int st = 0; st < 2; st++) {
            int kb = st * 64 + l16 * 16;
            int qrow = w * 16 + l15;
            bf16x8 a = *(const bf16x8*)(Qs + qrow * 128 + (kb ^ ((qrow & 7) << 4)));
#pragma unroll
            for (int n = 0; n < 4; n++) {
                int kr = n * 16 + l15;
                bf16x8 b = *(const bf16x8*)(Ks + kr * 128 + (kb ^ ((kr & 7) << 4)));
                s_acc[n] = __builtin_amdgcn_mfma_f32_16x16x32_bf16(a, b, s_acc[n], 0, 0, 0);
            }
        }
        char* pw = Ps + w * 2048;
#pragma unroll
        for (int j = 0; j < 4; j++) {
            float s0 = s_acc[0][j] * 0.125f, s1 = s_acc[1][j] * 0.125f;
            float s2 = s_acc[2][j] * 0.125f, s3 = s_acc[3][j] * 0.125f;
            float tmax = fmaxf(fmaxf(s0, s1), fmaxf(s2, s3));
#pragma unroll
            for (int o = 1; o < 16; o <<= 1) tmax = fmaxf(tmax, __shfl_xor(tmax, o));
            float mnew = fmaxf(m_r[j], tmax);
            float resc = __expf(m_r[j] - mnew);
            float p0 = __expf(s0 - mnew), p1 = __expf(s1 - mnew);
            float p2 = __expf(s2 - mnew), p3 = __expf(s3 - mnew);
            float ps = p0 + p1 + p2 + p3;
#pragma unroll
            for (int o = 1; o < 16; o <<= 1) ps += __shfl_xor(ps, o);
            l_r[j] = l_r[j] * resc + ps;
            m_r[j] = mnew;
            accO[0][j] *= resc; accO[1][j] *= resc;
            accO[2][j] *= resc; accO[3][j] *= resc;
            int prow = l16 * 4 + j;
            int sw = (prow & 7) << 4;
            *(unsigned short*)(pw + prow * 128 + ((2 * l15) ^ sw)) = f2bf(p0);
            *(unsigned short*)(pw + prow * 128 + ((2 * l15 + 32) ^ sw)) = f2bf(p1);
            *(unsigned short*)(pw + prow * 128 + ((2 * l15 + 64) ^ sw)) = f2bf(p2);
            *(unsigned short*)(pw + prow * 128 + ((2 * l15 + 96) ^ sw)) = f2bf(p3);
        }
#pragma unroll
        for (int st = 0; st < 2; st++) {
            int kb = st * 64 + l16 * 16;
            bf16x8 pa = *(const bf16x8*)(pw + l15 * 128 + (kb ^ ((l15 & 7) << 4)));
#pragma unroll
            for (int n = 0; n < 4; n++) {
                int vr = n * 16 + l15;
                bf16x8 vb = *(const bf16x8*)(Vs + vr * 128 + (kb ^ ((vr & 7) << 4)));
                accO[n] = __builtin_amdgcn_mfma_f32_16x16x32_bf16(pa, vb, accO[n], 0, 0, 0);
            }
        }
    }
    unsigned short* obase = O + (size_t)(bb * SEQ + qt * QBLK + w * 16) * DMODEL + hh * 64;
#pragma unroll
    for (int j = 0; j < 4; j++) {
        float inv = 1.f / l_r[j];
        int row = l16 * 4 + j;
#pragma unroll
        for (int n = 0; n < 4; n++)
            obase[(size_t)row * DMODEL + n * 16 + l15] = f2bf(accO[n][j] * inv);
    }
}

// ---------------- router: shuffle-reduced stats ----------------
__global__ __launch_bounds__(256) void router_topk(const float* __restrict__ rsc,
                                                   float* __restrict__ topw,
                                                   int* __restrict__ topi,
                                                   int* __restrict__ cnt,
                                                   float* __restrict__ sumP,
                                                   float* __restrict__ zacc) {
    __shared__ float wP[4][NEXP];
    __shared__ int wC[4][NEXP];
    __shared__ float wZ[4];
    int tid = threadIdx.x;
    int wv = tid >> 6, lane = tid & 63;
    int n = blockIdx.x * 256 + tid;
    float sc[NEXP];
    float mx = -1e30f;
#pragma unroll
    for (int e = 0; e < NEXP; e++) { sc[e] = rsc[n * NEXP + e]; mx = fmaxf(mx, sc[e]); }
    float se = 0.f;
#pragma unroll
    for (int e = 0; e < NEXP; e++) { sc[e] = expf(sc[e] - mx); se += sc[e]; }
    float invse = 1.f / se;
    float lse = mx + logf(se);
    float z = lse * lse;
#pragma unroll
    for (int o = 32; o; o >>= 1) z += __shfl_xor(z, o);
    if (lane == 0) wZ[wv] = z;
#pragma unroll
    for (int e = 0; e < NEXP; e++) {
        float pv = sc[e] * invse;
#pragma unroll
        for (int o = 32; o; o >>= 1) pv += __shfl_xor(pv, o);
        if (lane == 0) wP[wv][e] = pv;
    }
    float tv[TOPK]; int ti[TOPK];
#pragma unroll
    for (int k = 0; k < TOPK; k++) {
        float best = -1.f; int bi = 0;
#pragma unroll
        for (int e = 0; e < NEXP; e++) {
            if (sc[e] > best) { best = sc[e]; bi = e; }
        }
        tv[k] = best * invse; ti[k] = bi; sc[bi] = -1.f;
    }
    float s4 = tv[0] + tv[1] + tv[2] + tv[3];
#pragma unroll
    for (int k = 0; k < TOPK; k++) {
        topw[n * TOPK + k] = tv[k] / s4;
        topi[n * TOPK + k] = ti[k];
    }
#pragma unroll
    for (int e = 0; e < NEXP; e++) {
        unsigned long long b0 = __ballot(ti[0] == e);
        unsigned long long b1 = __ballot(ti[1] == e);
        unsigned long long b2 = __ballot(ti[2] == e);
        unsigned long long b3 = __ballot(ti[3] == e);
        if (lane == 0)
            wC[wv][e] = __popcll(b0) + __popcll(b1) + __popcll(b2) + __popcll(b3);
    }
    __syncthreads();
    if (tid < NEXP) {
        atomicAdd(&sumP[tid], wP[0][tid] + wP[1][tid] + wP[2][tid] + wP[3][tid]);
        atomicAdd(&cnt[tid], wC[0][tid] + wC[1][tid] + wC[2][tid] + wC[3][tid]);
    }
    if (tid == 0) atomicAdd(zacc, wZ[0] + wZ[1] + wZ[2] + wZ[3]);
}

// ---------------- scan (1 wave): padded offsets + tile map + pad-perm zero + aux ----------------
__global__ void scanaux_kernel(const int* __restrict__ cnt, int* __restrict__ poff,
                               int* __restrict__ tinfo, int* __restrict__ perm,
                               const float* __restrict__ sumP, const float* __restrict__ zacc,
                               float* __restrict__ out_aux, int l) {
    int lane = threadIdx.x;
    int c = (lane < NEXP) ? cnt[lane] : 0;
    int nt = (c + 127) >> 7;
    int x = nt;
#pragma unroll
    for (int o = 1; o < 32; o <<= 1) {
        int y = __shfl_up(x, o);
        if (lane >= o) x += y;
    }
    int excl = x - nt;
    if (lane < NEXP) {
        poff[lane] = excl * 128;
        for (int i = 0; i < nt; i++) {
            tinfo[1 + 2 * (excl + i)] = lane;
            tinfo[2 + 2 * (excl + i)] = i * 128;
        }
        // zero pad rows of perm (gl_lds gather safety; outputs discarded)
        for (int i = c; i < nt * 128; i++) perm[excl * 128 + i] = 0;
    }
    float lb = (lane < NEXP) ? ((float)c / (float)NTOK) * (sumP[lane] / (float)NTOK) : 0.f;
#pragma unroll
    for (int o = 32; o; o >>= 1) lb += __shfl_xor(lb, o);
    if (lane == 31) {
        tinfo[0] = x;
        out_aux[l] = lb * (float)NEXP / (float)TOPK;
        out_aux[NLAYER + l] = zacc[0] / (float)NTOK;
    }
}

// ---------------- scatter: LDS-aggregated per-block bases ----------------
__global__ __launch_bounds__(256) void scatter_kernel(const int* __restrict__ topi,
                                                      const int* __restrict__ poff,
                                                      int* __restrict__ cursor,
                                                      int* __restrict__ perm,
                                                      int* __restrict__ pos) {
    __shared__ int lcnt[NEXP];
    __shared__ int lbase[NEXP];
    if (threadIdx.x < NEXP) lcnt[threadIdx.x] = 0;
    __syncthreads();
    int i = blockIdx.x * 256 + threadIdx.x;
    int e = topi[i];
    int lr = atomicAdd(&lcnt[e], 1);
    __syncthreads();
    if (threadIdx.x < NEXP && lcnt[threadIdx.x] > 0)
        lbase[threadIdx.x] = atomicAdd(&cursor[threadIdx.x], lcnt[threadIdx.x]);
    __syncthreads();
    int g = poff[e] + lbase[e] + lr;
    perm[g] = i >> 2;
    pos[i] = g;
}

// ---------------- launcher ----------------
extern "C" void kernel_launch(void* const* d_in, const int* in_sizes, int n_in,
                              void* d_out, int out_size, void* d_ws, size_t ws_size,
                              hipStream_t stream) {
    (void)in_sizes; (void)n_in; (void)out_size; (void)ws_size;
    const float* x_in  = (const float*)d_in[0];
    const float* ln1_s = (const float*)d_in[1];
    const float* ln1_b = (const float*)d_in[2];
    const float* ln2_s = (const float*)d_in[3];
    const float* ln2_b = (const float*)d_in[4];
    const float* wq = (const float*)d_in[5];
    const float* bq = (const float*)d_in[6];
    const float* wk = (const float*)d_in[7];
    const float* bk = (const float*)d_in[8];
    const float* wv = (const float*)d_in[9];
    const float* bv = (const float*)d_in[10];
    const float* wo = (const float*)d_in[11];
    const float* bo = (const float*)d_in[12];
    const float* rdw = (const float*)d_in[13];
    const float* ruw = (const float*)d_in[14];
    const float* w1 = (const float*)d_in[15];
    const float* b1 = (const float*)d_in[16];
    const float* w2 = (const float*)d_in[17];
    const float* b2 = (const float*)d_in[18];
    const float* ws1 = (const float*)d_in[19];
    const float* bs1 = (const float*)d_in[20];
    const float* ws2 = (const float*)d_in[21];
    const float* bs2 = (const float*)d_in[22];
    const float* fn_s = (const float*)d_in[23];
    const float* fn_b = (const float*)d_in[24];

    float* ws = (float*)d_ws;
    const size_t ND = (size_t)NTOK * DMODEL;
    const size_t PADROWS = (size_t)MAXTILE * 128;
    size_t o = 0;
    float* xb  = ws + o; o += ND;
    float* h   = ws + o; o += ND;
    unsigned short* hb     = (unsigned short*)(ws + o); o += ND / 2;
    unsigned short* qkv_bf = (unsigned short*)(ws + o); o += (size_t)NTOK * 1536 / 2;
    unsigned short* vT     = (unsigned short*)(ws + o); o += ND / 2;
    unsigned short* t1b    = (unsigned short*)(ws + o); o += ND / 2;
    unsigned short* hidb   = (unsigned short*)(ws + o); o += (size_t)NTOK * HSHARED / 2;
    unsigned short* eogb   = (unsigned short*)(ws + o); o += PADROWS * DMODEL / 2;
    float* pbuf = ws + o; o += 4 * ND;                 // split-K partials (max SK=4)
    float* rdru = ws + o; o += (size_t)DMODEL * NEXP;
    float* rsc  = ws + o; o += (size_t)NTOK * NEXP;
    float* topw = ws + o; o += (size_t)NTOK * TOPK;
    float* bqkv = ws + o; o += 1536;
    int* topi = (int*)(ws + o); o += (size_t)NTOK * TOPK;
    int* pos  = (int*)(ws + o); o += (size_t)NTOK * TOPK;
    int* perm = (int*)(ws + o); o += PADROWS;
    int* stats = (int*)(ws + o); o += 256;
    int* tinfo = (int*)(ws + o); o += 512;
    int* cnt = stats;
    int* cursor = stats + 32;
    int* poff = stats + 64;
    float* sumP = (float*)(stats + 96);
    float* zacc = sumP + 32;
    unsigned short* wbf = (unsigned short*)(ws + o);
    const size_t DDu = (size_t)DMODEL * DMODEL;
    unsigned short* wqkvt = wbf;
    unsigned short* wot  = wqkvt + 3 * DDu;
    unsigned short* w1t  = wot + DDu;
    unsigned short* w2t  = w1t + (size_t)NEXP * DDu;
    unsigned short* ws1t = w2t + (size_t)NEXP * DDu;
    unsigned short* ws2t = ws1t + (size_t)DMODEL * HSHARED;

    float* out_x = (float*)d_out;
    float* out_aux = out_x + ND;

    hipMemcpyAsync(xb, x_in, ND * sizeof(float), hipMemcpyDeviceToDevice, stream);

    dim3 blk(256);
    dim3 gQKV(1536 / 64, NTOK / 128);           // 768 blocks
    dim3 gOP(DMODEL / 64, NTOK / 128, 2);       // 512 blocks
    dim3 gF2(DMODEL / 64, NTOK / 128, 4);       // 1024 blocks
    dim3 gHS(HSHARED / 64, NTOK / 128);         // 2048 blocks
    dim3 gE1(HEXP / 64, MAXTILE);               // 1280 blocks
    dim3 gE2(DMODEL / 64, MAXTILE);

    for (int l = 0; l < NLAYER; l++) {
        const size_t DD = (size_t)DMODEL * DMODEL;
        // ---- weight transpose+convert ----
        wt_kernel<<<dim3(8, 8, 1), blk, 0, stream>>>(wq + l * DD, wqkvt, DMODEL, DMODEL);
        wt_kernel<<<dim3(8, 8, 1), blk, 0, stream>>>(wk + l * DD, wqkvt + DDu, DMODEL, DMODEL);
        wt_kernel<<<dim3(8, 8, 1), blk, 0, stream>>>(wv + l * DD, wqkvt + 2 * DDu, DMODEL, DMODEL);
        wt_kernel<<<dim3(8, 8, 1), blk, 0, stream>>>(wo + l * DD, wot, DMODEL, DMODEL);
        wt_kernel<<<dim3(8, 8, NEXP), blk, 0, stream>>>(w1 + (size_t)l * NEXP * DD, w1t, DMODEL, HEXP);
        wt_kernel<<<dim3(8, 8, NEXP), blk, 0, stream>>>(w2 + (size_t)l * NEXP * DD, w2t, HEXP, DMODEL);
        wt_kernel<<<dim3(HSHARED / 64, 8, 1), blk, 0, stream>>>(ws1 + (size_t)l * DMODEL * HSHARED, ws1t, DMODEL, HSHARED);
        wt_kernel<<<dim3(8, HSHARED / 64, 1), blk, 0, stream>>>(ws2 + (size_t)l * HSHARED * DMODEL, ws2t, HSHARED, DMODEL);
        biaspack<<<6, blk, 0, stream>>>(bq + l * DMODEL, bk + l * DMODEL, bv + l * DMODEL, bqkv, stats);
        // ---- router weight fold: rdru = rd @ ru ----
        gemm_tile<false><<<dim3(1, 8), blk, 0, stream>>>(
            rdw + (size_t)l * DMODEL * RRANK, ruw + (size_t)l * RRANK * NEXP, rdru, DMODEL, NEXP, RRANK, RRANK);

        // ---- LN1 (layer 0 only; later layers fused into F2 reduceln) ----
        if (l == 0)
            ln_kernel<1><<<NTOK / 4, blk, 0, stream>>>(xb, ln1_s, ln1_b, nullptr, hb);
        // ---- fused QKV ----
        gemm_mfma<false, false, false, false, true><<<gQKV, blk, 0, stream>>>(
            hb, wqkvt, bqkv, nullptr, qkv_bf, NTOK, 1536, DMODEL, nullptr, nullptr, nullptr, nullptr);
        // ---- V transpose ----
        vtr_kernel<<<dim3(SEQ / 64, NHEAD, BATCH), blk, 0, stream>>>(qkv_bf, vT);
        // ---- MFMA attention ----
        attn_mfma<<<dim3(SEQ / QBLK, NHEAD, BATCH), blk, 0, stream>>>(qkv_bf, vT, t1b);
        // ---- out proj: split-K=2 + fused reduce+LN2 (xb updated; h,f32 + hb,bf16 out) ----
        gemm_mfma<false, false, false, false, false, 2><<<gOP, blk, 0, stream>>>(
            t1b, wot, nullptr, nullptr, pbuf, NTOK, DMODEL, DMODEL, nullptr, nullptr, nullptr, nullptr);
        reduceln_kernel<2, false, 2><<<NTOK / 4, blk, 0, stream>>>(
            pbuf, bo + l * DMODEL, nullptr, nullptr, nullptr, xb,
            ln2_s + l * DMODEL, ln2_b + l * DMODEL, h, hb);
        // ---- router ----
        gemm_tile<false><<<dim3(1, NTOK / 64), blk, 0, stream>>>(
            h, rdru, rsc, NTOK, NEXP, DMODEL, DMODEL);
        router_topk<<<NTOK / 256, blk, 0, stream>>>(rsc, topw, topi, cnt, sumP, zacc);
        scanaux_kernel<<<1, 64, 0, stream>>>(cnt, poff, tinfo, perm, sumP, zacc, out_aux, l);
        scatter_kernel<<<NTOK * TOPK / 256, blk, 0, stream>>>(topi, poff, cursor, perm, pos);
        // ---- expert FFN ----
        gemm_mfma<true, false, true, true, true><<<gE1, blk, 0, stream>>>(
            hb, w1t, b1 + (size_t)l * NEXP * HEXP, nullptr,
            hidb, 0, HEXP, DMODEL, perm, cnt, poff, tinfo);
        gemm_mfma<false, false, false, true, true><<<gE2, blk, 0, stream>>>(
            hidb, w2t, b2 + (size_t)l * NEXP * DMODEL, nullptr,
            eogb, 0, DMODEL, HEXP, nullptr, cnt, poff, tinfo);
        // ---- shared FFN1 ----
        gemm_mfma<true, false, false, false, true><<<gHS, blk, 0, stream>>>(
            hb, ws1t, bs1 + (size_t)l * HSHARED, nullptr,
            hidb, NTOK, HSHARED, DMODEL, nullptr, nullptr, nullptr, nullptr);
        // ---- shared FFN2: split-K=4 + fused reduce+MoE-combine+LN(next layer or final) ----
        gemm_mfma<false, false, false, false, false, 4><<<gF2, blk, 0, stream>>>(
            hidb, ws2t, nullptr, nullptr, pbuf, NTOK, DMODEL, HSHARED, nullptr, nullptr, nullptr, nullptr);
        if (l + 1 < NLAYER) {
            reduceln_kernel<4, true, 1><<<NTOK / 4, blk, 0, stream>>>(
                pbuf, bs2 + l * DMODEL, eogb, topw, pos, xb,
                ln1_s + (l + 1) * DMODEL, ln1_b + (l + 1) * DMODEL, nullptr, hb);
        } else {
            reduceln_kernel<4, true, 0><<<NTOK / 4, blk, 0, stream>>>(
                pbuf, bs2 + l * DMODEL, eogb, topw, pos, xb,
                fn_s, fn_b, out_x, nullptr);
        }
    }
}

// Round 15
// 567.271 us; speedup vs baseline: 1.1406x; 1.0745x over previous
//
#include <hip/hip_runtime.h>
#include <math.h>

// ---- problem constants ----
#define NTOK    4096      // B*S
#define DMODEL  512
#define NEXP    32
#define RRANK   64
#define HEXP    512
#define HSHARED 4096
#define SEQ     1024
#define BATCH   4
#define NHEAD   8
#define TOPK    4
#define NLAYER  2
#define QBLK    64
#define KBLK    64
#define MAXTILE 160       // max padded expert m-tiles: 16384/128 + 32
#define DDU     262144    // 512*512

typedef __attribute__((ext_vector_type(8))) short bf16x8;
typedef __attribute__((ext_vector_type(4))) float f32x4;

__device__ __forceinline__ float gelu_f(float x) {
    float t = tanhf(0.7978845608028654f * (x + 0.044715f * x * x * x));
    return 0.5f * x * (1.f + t);
}
__device__ __forceinline__ unsigned short f2bf(float f) {
    unsigned int u = __float_as_uint(f);
    u += 0x7FFFu + ((u >> 16) & 1u);
    return (unsigned short)(u >> 16);
}
__device__ __forceinline__ float bf2f(unsigned short u) {
    return __uint_as_float((unsigned int)u << 16);
}
// async global->LDS, 16B per lane; LDS dest wave-uniform base + lane*16
__device__ __forceinline__ void gl_lds16(const void* g, void* l) {
    __builtin_amdgcn_global_load_lds(
        (const __attribute__((address_space(1))) void*)g,
        (__attribute__((address_space(3))) void*)l, 16, 0, 0);
}

// ---------------- LayerNorm (standalone, layer-0 entry only) ----------------
template <int MODE>
__global__ __launch_bounds__(256) void ln_kernel(const float* __restrict__ x,
                                                 const float* __restrict__ s,
                                                 const float* __restrict__ b,
                                                 float* __restrict__ outf,
                                                 unsigned short* __restrict__ outb) {
    int wave = threadIdx.x >> 6, lane = threadIdx.x & 63;
    int row = blockIdx.x * 4 + wave;
    const float* xr = x + (size_t)row * DMODEL;
    float v[8];
    float sum = 0.f;
#pragma unroll
    for (int i = 0; i < 8; i++) { v[i] = xr[lane + i * 64]; sum += v[i]; }
#pragma unroll
    for (int o = 32; o; o >>= 1) sum += __shfl_xor(sum, o);
    float m = sum * (1.f / DMODEL);
    float vs = 0.f;
#pragma unroll
    for (int i = 0; i < 8; i++) { float d = v[i] - m; vs += d * d; }
#pragma unroll
    for (int o = 32; o; o >>= 1) vs += __shfl_xor(vs, o);
    float rstd = rsqrtf(vs * (1.f / DMODEL) + 1e-5f);
#pragma unroll
    for (int i = 0; i < 8; i++) {
        int c = lane + i * 64;
        float r = (v[i] - m) * rstd * s[c] + b[c];
        if (MODE != 1) outf[(size_t)row * DMODEL + c] = r;
        if (MODE != 0) outb[(size_t)row * DMODEL + c] = f2bf(r);
    }
}

// ---------------- fused split-K reduce (+bias +residual +MoE) + LayerNorm (+router scores) ----------------
// One wave per row. Updates xb in place, LN -> outf/outb per MODE.
// ROUTER: also computes rsc[row][e] = LN_row . rdru[:,e]  (fp32, exact class as old fp32 GEMM).
template <int SK, bool MOE, int MODE, bool ROUTER = false>
__global__ __launch_bounds__(256) void reduceln_kernel(
    const float* __restrict__ pbuf, const float* __restrict__ bias,
    const unsigned short* __restrict__ eogb, const float* __restrict__ topw,
    const int* __restrict__ pos, float* __restrict__ xb,
    const float* __restrict__ s, const float* __restrict__ b,
    float* __restrict__ outf, unsigned short* __restrict__ outb,
    const float* __restrict__ rdru, float* __restrict__ rsc) {
    int wave = threadIdx.x >> 6, lane = threadIdx.x & 63;
    int row = blockIdx.x * 4 + wave;
    int cb = lane * 8;
    size_t base = (size_t)row * DMODEL + cb;
    float v[8];
    {
        float4 a0 = *(const float4*)(xb + base);
        float4 a1 = *(const float4*)(xb + base + 4);
        float4 b0 = *(const float4*)(bias + cb);
        float4 b1 = *(const float4*)(bias + cb + 4);
        v[0] = a0.x + b0.x; v[1] = a0.y + b0.y; v[2] = a0.z + b0.z; v[3] = a0.w + b0.w;
        v[4] = a1.x + b1.x; v[5] = a1.y + b1.y; v[6] = a1.z + b1.z; v[7] = a1.w + b1.w;
    }
#pragma unroll
    for (int sk = 0; sk < SK; sk++) {
        const float* p = pbuf + (size_t)sk * NTOK * DMODEL + base;
        float4 p0 = *(const float4*)p;
        float4 p1 = *(const float4*)(p + 4);
        v[0] += p0.x; v[1] += p0.y; v[2] += p0.z; v[3] += p0.w;
        v[4] += p1.x; v[5] += p1.y; v[6] += p1.z; v[7] += p1.w;
    }
    if (MOE) {
#pragma unroll
        for (int k = 0; k < TOPK; k++) {
            float w = topw[row * TOPK + k];
            bf16x8 e = *(const bf16x8*)(eogb + (size_t)pos[row * TOPK + k] * DMODEL + cb);
#pragma unroll
            for (int i = 0; i < 8; i++) v[i] += w * bf2f((unsigned short)e[i]);
        }
    }
    *(float4*)(xb + base) = make_float4(v[0], v[1], v[2], v[3]);
    *(float4*)(xb + base + 4) = make_float4(v[4], v[5], v[6], v[7]);
    float sum = 0.f;
#pragma unroll
    for (int i = 0; i < 8; i++) sum += v[i];
#pragma unroll
    for (int o = 32; o; o >>= 1) sum += __shfl_xor(sum, o);
    float m = sum * (1.f / DMODEL);
    float vs = 0.f;
#pragma unroll
    for (int i = 0; i < 8; i++) { float d = v[i] - m; vs += d * d; }
#pragma unroll
    for (int o = 32; o; o >>= 1) vs += __shfl_xor(vs, o);
    float rstd = rsqrtf(vs * (1.f / DMODEL) + 1e-5f);
    float rr[8];
#pragma unroll
    for (int i = 0; i < 8; i++) {
        int c = cb + i;
        rr[i] = (v[i] - m) * rstd * s[c] + b[c];
        if (MODE != 1) outf[(size_t)row * DMODEL + c] = rr[i];
        if (MODE != 0) outb[(size_t)row * DMODEL + c] = f2bf(rr[i]);
    }
    if (ROUTER) {
        float sc[NEXP];
#pragma unroll
        for (int e = 0; e < NEXP; e++) sc[e] = 0.f;
#pragma unroll
        for (int i = 0; i < 8; i++) {
            const float4* rp = (const float4*)(rdru + (size_t)(cb + i) * NEXP);
            float rv = rr[i];
#pragma unroll
            for (int e4 = 0; e4 < 8; e4++) {
                float4 q = rp[e4];
                sc[e4 * 4 + 0] += rv * q.x;
                sc[e4 * 4 + 1] += rv * q.y;
                sc[e4 * 4 + 2] += rv * q.z;
                sc[e4 * 4 + 3] += rv * q.w;
            }
        }
#pragma unroll
        for (int e = 0; e < NEXP; e++) {
#pragma unroll
            for (int o = 32; o; o >>= 1) sc[e] += __shfl_xor(sc[e], o);
        }
        if (lane == 0) {
            float* rp = rsc + (size_t)row * NEXP;
#pragma unroll
            for (int e = 0; e < NEXP; e++) rp[e] = sc[e];
        }
    }
}

// ---------------- ALL weight transposes + biaspack + stats-zero in ONE launch ----------------
// Flat block ranges: [0,256) wq/wk/wv/wo  [256,2304) w1  [2304,4352) w2
// [4352,4864) ws1  [4864,5376) ws2  [5376,5382) biaspack+stats.
__global__ __launch_bounds__(256) void wtall_kernel(
    const float* __restrict__ wq, const float* __restrict__ wk,
    const float* __restrict__ wv, const float* __restrict__ wo,
    const float* __restrict__ w1, const float* __restrict__ w2,
    const float* __restrict__ ws1, const float* __restrict__ ws2,
    const float* __restrict__ bq, const float* __restrict__ bk, const float* __restrict__ bv,
    unsigned short* __restrict__ wqkvt, unsigned short* __restrict__ wot,
    unsigned short* __restrict__ w1t, unsigned short* __restrict__ w2t,
    unsigned short* __restrict__ ws1t, unsigned short* __restrict__ ws2t,
    float* __restrict__ bqkv, int* __restrict__ stats) {
    __shared__ float tbuf[64][68];
    int bkid = blockIdx.x;
    int tid = threadIdx.x;
    if (bkid >= 5376) {
        int i = (bkid - 5376) * 256 + tid;
        float val = (i < 512) ? bq[i] : (i < 1024 ? bk[i - 512] : bv[i - 1024]);
        bqkv[i] = val;
        if (i < 160) stats[i] = 0;
        return;
    }
    const float* src;
    unsigned short* dst;
    int K, N, tx, ty;
    if (bkid < 256) {
        int w = bkid >> 6, t = bkid & 63;
        K = 512; N = 512; ty = t >> 3; tx = t & 7;
        if (w == 0)      { src = wq; dst = wqkvt; }
        else if (w == 1) { src = wk; dst = wqkvt + DDU; }
        else if (w == 2) { src = wv; dst = wqkvt + 2 * (size_t)DDU; }
        else             { src = wo; dst = wot; }
    } else if (bkid < 2304) {
        int t = bkid - 256; int e = t >> 6; int tt = t & 63;
        K = 512; N = 512; ty = tt >> 3; tx = tt & 7;
        src = w1 + (size_t)e * DDU; dst = w1t + (size_t)e * DDU;
    } else if (bkid < 4352) {
        int t = bkid - 2304; int e = t >> 6; int tt = t & 63;
        K = 512; N = 512; ty = tt >> 3; tx = tt & 7;
        src = w2 + (size_t)e * DDU; dst = w2t + (size_t)e * DDU;
    } else if (bkid < 4864) {
        int t = bkid - 4352;
        K = 512; N = 4096; tx = t & 63; ty = t >> 6;
        src = ws1; dst = ws1t;
    } else {
        int t = bkid - 4864;
        K = 4096; N = 512; tx = t & 7; ty = t >> 3;
        src = ws2; dst = ws2t;
    }
    int k0 = ty * 64, n0 = tx * 64;
    int r = tid >> 2, cb4 = (tid & 3) * 4;
#pragma unroll
    for (int i = 0; i < 4; i++)
        *(float4*)&tbuf[r][cb4 + i * 16] = *(const float4*)(src + (size_t)(k0 + r) * N + n0 + cb4 + i * 16);
    __syncthreads();
    int g = tid & 7, nr = tid >> 3;
#pragma unroll
    for (int i = 0; i < 2; i++) {
        int n = nr + i * 32;
        bf16x8 v;
#pragma unroll
        for (int j = 0; j < 8; j++) v[j] = (short)f2bf(tbuf[g * 8 + j][n]);
        *(bf16x8*)(dst + (size_t)(n0 + n) * K + k0 + g * 8) = v;
    }
}

// ---------------- V transpose: qkv[.,1024+h*64+d] -> Vt[b,h,d,s] (bf16) ----------------
__global__ __launch_bounds__(256) void vtr_kernel(const unsigned short* __restrict__ QKV,
                                                  unsigned short* __restrict__ Vt) {
    int st = blockIdx.x, hh = blockIdx.y, bb = blockIdx.z;
    __shared__ unsigned short t[64][72];
    int r = threadIdx.x >> 3, g = threadIdx.x & 7;
#pragma unroll
    for (int i = 0; i < 2; i++) {
        int row = r + i * 32;
        bf16x8 v = *(const bf16x8*)(QKV + (size_t)(bb * SEQ + st * 64 + row) * 1536 + 1024 + hh * 64 + g * 8);
        *(bf16x8*)&t[row][g * 8] = v;
    }
    __syncthreads();
#pragma unroll
    for (int i = 0; i < 2; i++) {
        int d = r + i * 32;
        bf16x8 v;
#pragma unroll
        for (int j = 0; j < 8; j++) v[j] = (short)t[g * 8 + j][d];
        *(bf16x8*)(Vt + (size_t)((bb * NHEAD + hh) * 64 + d) * SEQ + st * 64 + g * 8) = v;
    }
}

// ---------------- bf16 MFMA GEMM: 128x64 tile, BK=64 (R12/R14 proven config) ----------------
template <bool GELU, bool DORES, bool GATHER, bool EXPERT, bool OUTBF16, int SK = 1, int BK = 64>
__global__ __launch_bounds__(256, 2) void gemm_mfma(
    const unsigned short* __restrict__ Ab, const unsigned short* __restrict__ Wt,
    const float* __restrict__ bias, const float* __restrict__ res,
    void* __restrict__ Cvoid, int M, int Nn, int Kk,
    const int* __restrict__ rowmap, const int* __restrict__ cntp,
    const int* __restrict__ offp, const int* __restrict__ tinfo) {
    constexpr int RS  = BK * 2;
    constexpr int CH  = RS / 16;
    constexpr int RPI = 1024 / RS;
    constexpr int AIW = 32 / RPI;
    constexpr int BIW = 16 / RPI;
    unsigned int bid = blockIdx.y * gridDim.x + blockIdx.x;
    unsigned int tot = gridDim.x * gridDim.y;
    unsigned int lg = (bid & 7) * (tot >> 3) + (bid >> 3);
    unsigned int bx = lg % gridDim.x;
    unsigned int by = lg / gridDim.x;
    int n0 = bx * 64;
    int m0;
    size_t cbase = 0;
    int kbeg = 0, kend = Kk;
    if (EXPERT) {
        int t = by;
        if (t >= tinfo[0]) return;
        int e = tinfo[1 + 2 * t];
        m0 = tinfo[2 + 2 * t];
        M = cntp[e];
        Wt += (size_t)e * Nn * Kk;
        bias += (size_t)e * Nn;
        int oe = offp[e];
        cbase = (size_t)oe * Nn;
        if (GATHER) rowmap += oe;
        else Ab += (size_t)oe * Kk;
    } else {
        m0 = by * 128;
    }
    if (SK > 1) {
        int s = blockIdx.z;
        int chunk = Kk / SK;
        kbeg = s * chunk;
        kend = kbeg + chunk;
        cbase = (size_t)s * M * Nn;
    }
    __shared__ short As[128 * BK];
    __shared__ short Bs[64 * BK];
    char* asb = (char*)As;
    char* bsb = (char*)Bs;
    int tid = threadIdx.x;
    int wave = tid >> 6, lane = tid & 63;
    int wm = wave >> 1, wn = wave & 1;
    int l15 = lane & 15, l16 = lane >> 4;
    int c16 = lane & (CH - 1);
    int ro  = lane / CH;

    const char* aptr[AIW];
    const char* bptr[BIW];
#pragma unroll
    for (int j = 0; j < AIW; j++) {
        int rloc = j * RPI + ro;
        int row = wave * 32 + rloc;
        int grow = m0 + row;
        int arow = GATHER ? rowmap[grow] : grow;
        int srcoff = ((c16 ^ (rloc & (CH - 1))) << 4);
        aptr[j] = (const char*)Ab + (((size_t)arow * Kk) << 1) + srcoff;
    }
#pragma unroll
    for (int j = 0; j < BIW; j++) {
        int rloc = j * RPI + ro;
        int row = wave * 16 + rloc;
        int srcoff = ((c16 ^ (rloc & (CH - 1))) << 4);
        bptr[j] = (const char*)Wt + (((size_t)(n0 + row) * Kk) << 1) + srcoff;
    }

    f32x4 acc[4][2];
#pragma unroll
    for (int m = 0; m < 4; m++)
#pragma unroll
        for (int n = 0; n < 2; n++)
#pragma unroll
            for (int j = 0; j < 4; j++) acc[m][n][j] = 0.f;

    for (int k0 = kbeg; k0 < kend; k0 += BK) {
        size_t kb = (size_t)k0 << 1;
#pragma unroll
        for (int j = 0; j < AIW; j++) gl_lds16(aptr[j] + kb, asb + wave * 32 * RS + j * 1024);
#pragma unroll
        for (int j = 0; j < BIW; j++) gl_lds16(bptr[j] + kb, bsb + wave * 16 * RS + j * 1024);
        __syncthreads();
#pragma unroll
        for (int kk = 0; kk < BK / 32; kk++) {
            int k8 = kk * 4 + l16;
            bf16x8 a[4], b[2];
#pragma unroll
            for (int m = 0; m < 4; m++) {
                int row = wm * 64 + m * 16 + l15;
                a[m] = *(const bf16x8*)(asb + row * RS + ((k8 * 16) ^ ((row & (CH - 1)) << 4)));
            }
#pragma unroll
            for (int n = 0; n < 2; n++) {
                int row = wn * 32 + n * 16 + l15;
                b[n] = *(const bf16x8*)(bsb + row * RS + ((k8 * 16) ^ ((row & (CH - 1)) << 4)));
            }
#pragma unroll
            for (int m = 0; m < 4; m++)
#pragma unroll
                for (int n = 0; n < 2; n++)
                    acc[m][n] = __builtin_amdgcn_mfma_f32_16x16x32_bf16(a[m], b[n], acc[m][n], 0, 0, 0);
        }
        __syncthreads();
    }

#pragma unroll
    for (int m = 0; m < 4; m++) {
#pragma unroll
        for (int n = 0; n < 2; n++) {
            int col = n0 + wn * 32 + n * 16 + l15;
            float bv = (SK == 1 && bias) ? bias[col] : 0.f;
#pragma unroll
            for (int j = 0; j < 4; j++) {
                int row = m0 + wm * 64 + m * 16 + l16 * 4 + j;
                if (row >= M) continue;
                float val = acc[m][n][j] + bv;
                if (SK == 1 && GELU) val = gelu_f(val);
                if (SK == 1 && DORES) val += res[(size_t)row * Nn + col];
                if (SK == 1 && OUTBF16)
                    ((unsigned short*)Cvoid)[cbase + (size_t)row * Nn + col] = f2bf(val);
                else
                    ((float*)Cvoid)[cbase + (size_t)row * Nn + col] = val;
            }
        }
    }
}

// ---------------- small fp32 GEMM (rdru fold only) ----------------
template <bool GELU>
__global__ __launch_bounds__(256) void gemm_tile(
    const float* __restrict__ A, const float* __restrict__ W,
    float* __restrict__ C, int M, int Nn, int Kk, int lda) {
    int n0 = blockIdx.x * 64;
    int m0 = blockIdx.y * 64;
    __shared__ float Asf[16][68];
    __shared__ float Wsf[16][68];
    int tid = threadIdx.x;
    int ml = tid >> 2, kl = (tid & 3) << 2;
    bool avalid = (m0 + ml) < M;
    int arow = m0 + ml;
    const float* aptr = A + (size_t)arow * lda + kl;
    int kr = tid >> 4, nc = (tid & 15) << 2;
    bool wvalid = (n0 + nc) < Nn;
    const float* wptr = W + (size_t)kr * Nn + n0 + nc;
    int tm = (tid >> 4) << 2, tn = (tid & 15) << 2;
    float acc[4][4] = {{0.f}};
    for (int k0 = 0; k0 < Kk; k0 += 16) {
        float4 av = make_float4(0.f, 0.f, 0.f, 0.f);
        float4 wv = make_float4(0.f, 0.f, 0.f, 0.f);
        if (avalid) av = *(const float4*)(aptr + k0);
        if (wvalid) wv = *(const float4*)(wptr + (size_t)k0 * Nn);
        Asf[kl + 0][ml] = av.x; Asf[kl + 1][ml] = av.y;
        Asf[kl + 2][ml] = av.z; Asf[kl + 3][ml] = av.w;
        *(float4*)&Wsf[kr][nc] = wv;
        __syncthreads();
#pragma unroll
        for (int kk = 0; kk < 16; kk++) {
            float4 a4 = *(const float4*)&Asf[kk][tm];
            float4 w4 = *(const float4*)&Wsf[kk][tn];
            acc[0][0] += a4.x * w4.x; acc[0][1] += a4.x * w4.y; acc[0][2] += a4.x * w4.z; acc[0][3] += a4.x * w4.w;
            acc[1][0] += a4.y * w4.x; acc[1][1] += a4.y * w4.y; acc[1][2] += a4.y * w4.z; acc[1][3] += a4.y * w4.w;
            acc[2][0] += a4.z * w4.x; acc[2][1] += a4.z * w4.y; acc[2][2] += a4.z * w4.z; acc[2][3] += a4.z * w4.w;
            acc[3][0] += a4.w * w4.x; acc[3][1] += a4.w * w4.y; acc[3][2] += a4.w * w4.z; acc[3][3] += a4.w * w4.w;
        }
        __syncthreads();
    }
#pragma unroll
    for (int i = 0; i < 4; i++) {
        int mm = m0 + tm + i;
        if (mm >= M) break;
        float* crow = C + (size_t)mm * Nn;
#pragma unroll
        for (int j = 0; j < 4; j++) {
            int nn = n0 + tn + j;
            if (nn >= Nn) continue;
            float val = acc[i][j];
            if (GELU) val = gelu_f(val);
            crow[nn] = val;
        }
    }
}

// ---------------- MFMA flash attention: block = (64 q-rows, head, batch), 4 waves ----------------
__global__ __launch_bounds__(256, 2) void attn_mfma(const unsigned short* __restrict__ QKV,
                                                    const unsigned short* __restrict__ Vt,
                                                    unsigned short* __restrict__ O) {
    int qt = blockIdx.x, hh = blockIdx.y, bb = blockIdx.z;
    __shared__ char lds[32768];
    char* Qs = lds;
    char* Ks = lds + 8192;
    char* Vs = lds + 16384;
    char* Ps = lds + 24576;
    int tid = threadIdx.x;
    int w = tid >> 6, l = tid & 63;
    int l15 = l & 15, l16 = l >> 4;

    {
        int r = tid >> 3, g = tid & 7;
        const unsigned short* qbase = QKV + (size_t)(bb * SEQ + qt * QBLK) * 1536 + hh * 64;
#pragma unroll
        for (int i = 0; i < 2; i++) {
            int row = r + i * 32;
            bf16x8 v = *(const bf16x8*)(qbase + (size_t)row * 1536 + g * 8);
            *(bf16x8*)(Qs + row * 128 + ((g * 16) ^ ((row & 7) << 4))) = v;
        }
    }
    f32x4 accO[4];
#pragma unroll
    for (int n = 0; n < 4; n++)
#pragma unroll
        for (int j = 0; j < 4; j++) accO[n][j] = 0.f;
    float m_r[4] = {-1e30f, -1e30f, -1e30f, -1e30f};
    float l_r[4] = {0.f, 0.f, 0.f, 0.f};

    const unsigned short* kbase = QKV + (size_t)(bb * SEQ) * 1536 + 512 + hh * 64;
    const unsigned short* vbase = Vt + (size_t)((bb * NHEAD + hh) * 64) * SEQ;

    for (int kt = 0; kt < SEQ / KBLK; kt++) {
        __syncthreads();
        {
            int r = tid >> 3, g = tid & 7;
#pragma unroll
            for (int i = 0; i < 2; i++) {
                int row = r + i * 32;
                bf16x8 kv = *(const bf16x8*)(kbase + (size_t)(kt * KBLK + row) * 1536 + g * 8);
                *(bf16x8*)(Ks + row * 128 + ((g * 16) ^ ((row & 7) << 4))) = kv;
                bf16x8 vv = *(const bf16x8*)(vbase + (size_t)row * SEQ + kt * KBLK + g * 8);
                *(bf16x8*)(Vs + row * 128 + ((g * 16) ^ ((row & 7) << 4))) = vv;
            }
        }
        __syncthreads();
        f32x4 s_acc[4];
#pragma unroll
        for (int n = 0; n < 4; n++)
#pragma unroll
            for (int j = 0; j < 4; j++) s_acc[n][j] = 0.f;
#pragma unroll
        for (int st = 0; st < 2; st++) {
            int kb = st * 64 + l16 * 16;
            int qrow = w * 16 + l15;
            bf16x8 a = *(const bf16x8*)(Qs + qrow * 128 + (kb ^ ((qrow & 7) << 4)));
#pragma unroll
            for (int n = 0; n < 4; n++) {
                int kr = n * 16 + l15;
                bf16x8 b = *(const bf16x8*)(Ks + kr * 128 + (kb ^ ((kr & 7) << 4)));
                s_acc[n] = __builtin_amdgcn_mfma_f32_16x16x32_bf16(a, b, s_acc[n], 0, 0, 0);
            }
        }
        char* pw = Ps + w * 2048;
#pragma unroll
        for (int j = 0; j < 4; j++) {
            float s0 = s_acc[0][j] * 0.125f, s1 = s_acc[1][j] * 0.125f;
            float s2 = s_acc[2][j] * 0.125f, s3 = s_acc[3][j] * 0.125f;
            float tmax = fmaxf(fmaxf(s0, s1), fmaxf(s2, s3));
#pragma unroll
            for (int o = 1; o < 16; o <<= 1) tmax = fmaxf(tmax, __shfl_xor(tmax, o));
            float mnew = fmaxf(m_r[j], tmax);
            float resc = __expf(m_r[j] - mnew);
            float p0 = __expf(s0 - mnew), p1 = __expf(s1 - mnew);
            float p2 = __expf(s2 - mnew), p3 = __expf(s3 - mnew);
            float ps = p0 + p1 + p2 + p3;
#pragma unroll
            for (int o = 1; o < 16; o <<= 1) ps += __shfl_xor(ps, o);
            l_r[j] = l_r[j] * resc + ps;
            m_r[j] = mnew;
            accO[0][j] *= resc; accO[1][j] *= resc;
            accO[2][j] *= resc; accO[3][j] *= resc;
            int prow = l16 * 4 + j;
            int sw = (prow & 7) << 4;
            *(unsigned short*)(pw + prow * 128 + ((2 * l15) ^ sw)) = f2bf(p0);
            *(unsigned short*)(pw + prow * 128 + ((2 * l15 + 32) ^ sw)) = f2bf(p1);
            *(unsigned short*)(pw + prow * 128 + ((2 * l15 + 64) ^ sw)) = f2bf(p2);
            *(unsigned short*)(pw + prow * 128 + ((2 * l15 + 96) ^ sw)) = f2bf(p3);
        }
#pragma unroll
        for (int st = 0; st < 2; st++) {
            int kb = st * 64 + l16 * 16;
            bf16x8 pa = *(const bf16x8*)(pw + l15 * 128 + (kb ^ ((l15 & 7) << 4)));
#pragma unroll
            for (int n = 0; n < 4; n++) {
                int vr = n * 16 + l15;
                bf16x8 vb = *(const bf16x8*)(Vs + vr * 128 + (kb ^ ((vr & 7) << 4)));
                accO[n] = __builtin_amdgcn_mfma_f32_16x16x32_bf16(pa, vb, accO[n], 0, 0, 0);
            }
        }
    }
    unsigned short* obase = O + (size_t)(bb * SEQ + qt * QBLK + w * 16) * DMODEL + hh * 64;
#pragma unroll
    for (int j = 0; j < 4; j++) {
        float inv = 1.f / l_r[j];
        int row = l16 * 4 + j;
#pragma unroll
        for (int n = 0; n < 4; n++)
            obase[(size_t)row * DMODEL + n * 16 + l15] = f2bf(accO[n][j] * inv);
    }
}

// ---------------- router: shuffle-reduced stats ----------------
__global__ __launch_bounds__(256) void router_topk(const float* __restrict__ rsc,
                                                   float* __restrict__ topw,
                                                   int* __restrict__ topi,
                                                   int* __restrict__ cnt,
                                                   float* __restrict__ sumP,
                                                   float* __restrict__ zacc) {
    __shared__ float wP[4][NEXP];
    __shared__ int wC[4][NEXP];
    __shared__ float wZ[4];
    int tid = threadIdx.x;
    int wv = tid >> 6, lane = tid & 63;
    int n = blockIdx.x * 256 + tid;
    float sc[NEXP];
    float mx = -1e30f;
#pragma unroll
    for (int e = 0; e < NEXP; e++) { sc[e] = rsc[n * NEXP + e]; mx = fmaxf(mx, sc[e]); }
    float se = 0.f;
#pragma unroll
    for (int e = 0; e < NEXP; e++) { sc[e] = expf(sc[e] - mx); se += sc[e]; }
    float invse = 1.f / se;
    float lse = mx + logf(se);
    float z = lse * lse;
#pragma unroll
    for (int o = 32; o; o >>= 1) z += __shfl_xor(z, o);
    if (lane == 0) wZ[wv] = z;
#pragma unroll
    for (int e = 0; e < NEXP; e++) {
        float pv = sc[e] * invse;
#pragma unroll
        for (int o = 32; o; o >>= 1) pv += __shfl_xor(pv, o);
        if (lane == 0) wP[wv][e] = pv;
    }
    float tv[TOPK]; int ti[TOPK];
#pragma unroll
    for (int k = 0; k < TOPK; k++) {
        float best = -1.f; int bi = 0;
#pragma unroll
        for (int e = 0; e < NEXP; e++) {
            if (sc[e] > best) { best = sc[e]; bi = e; }
        }
        tv[k] = best * invse; ti[k] = bi; sc[bi] = -1.f;
    }
    float s4 = tv[0] + tv[1] + tv[2] + tv[3];
#pragma unroll
    for (int k = 0; k < TOPK; k++) {
        topw[n * TOPK + k] = tv[k] / s4;
        topi[n * TOPK + k] = ti[k];
    }
#pragma unroll
    for (int e = 0; e < NEXP; e++) {
        unsigned long long b0 = __ballot(ti[0] == e);
        unsigned long long b1 = __ballot(ti[1] == e);
        unsigned long long b2 = __ballot(ti[2] == e);
        unsigned long long b3 = __ballot(ti[3] == e);
        if (lane == 0)
            wC[wv][e] = __popcll(b0) + __popcll(b1) + __popcll(b2) + __popcll(b3);
    }
    __syncthreads();
    if (tid < NEXP) {
        atomicAdd(&sumP[tid], wP[0][tid] + wP[1][tid] + wP[2][tid] + wP[3][tid]);
        atomicAdd(&cnt[tid], wC[0][tid] + wC[1][tid] + wC[2][tid] + wC[3][tid]);
    }
    if (tid == 0) atomicAdd(zacc, wZ[0] + wZ[1] + wZ[2] + wZ[3]);
}

// ---------------- scan (1 wave): padded offsets + tile map + pad-perm zero + aux ----------------
__global__ void scanaux_kernel(const int* __restrict__ cnt, int* __restrict__ poff,
                               int* __restrict__ tinfo, int* __restrict__ perm,
                               const float* __restrict__ sumP, const float* __restrict__ zacc,
                               float* __restrict__ out_aux, int l) {
    int lane = threadIdx.x;
    int c = (lane < NEXP) ? cnt[lane] : 0;
    int nt = (c + 127) >> 7;
    int x = nt;
#pragma unroll
    for (int o = 1; o < 32; o <<= 1) {
        int y = __shfl_up(x, o);
        if (lane >= o) x += y;
    }
    int excl = x - nt;
    if (lane < NEXP) {
        poff[lane] = excl * 128;
        for (int i = 0; i < nt; i++) {
            tinfo[1 + 2 * (excl + i)] = lane;
            tinfo[2 + 2 * (excl + i)] = i * 128;
        }
        for (int i = c; i < nt * 128; i++) perm[excl * 128 + i] = 0;
    }
    float lb = (lane < NEXP) ? ((float)c / (float)NTOK) * (sumP[lane] / (float)NTOK) : 0.f;
#pragma unroll
    for (int o = 32; o; o >>= 1) lb += __shfl_xor(lb, o);
    if (lane == 31) {
        tinfo[0] = x;
        out_aux[l] = lb * (float)NEXP / (float)TOPK;
        out_aux[NLAYER + l] = zacc[0] / (float)NTOK;
    }
}

// ---------------- scatter: LDS-aggregated per-block bases ----------------
__global__ __launch_bounds__(256) void scatter_kernel(const int* __restrict__ topi,
                                                      const int* __restrict__ poff,
                                                      int* __restrict__ cursor,
                                                      int* __restrict__ perm,
                                                      int* __restrict__ pos) {
    __shared__ int lcnt[NEXP];
    __shared__ int lbase[NEXP];
    if (threadIdx.x < NEXP) lcnt[threadIdx.x] = 0;
    __syncthreads();
    int i = blockIdx.x * 256 + threadIdx.x;
    int e = topi[i];
    int lr = atomicAdd(&lcnt[e], 1);
    __syncthreads();
    if (threadIdx.x < NEXP && lcnt[threadIdx.x] > 0)
        lbase[threadIdx.x] = atomicAdd(&cursor[threadIdx.x], lcnt[threadIdx.x]);
    __syncthreads();
    int g = poff[e] + lbase[e] + lr;
    perm[g] = i >> 2;
    pos[i] = g;
}

// ---------------- launcher ----------------
extern "C" void kernel_launch(void* const* d_in, const int* in_sizes, int n_in,
                              void* d_out, int out_size, void* d_ws, size_t ws_size,
                              hipStream_t stream) {
    (void)in_sizes; (void)n_in; (void)out_size; (void)ws_size;
    const float* x_in  = (const float*)d_in[0];
    const float* ln1_s = (const float*)d_in[1];
    const float* ln1_b = (const float*)d_in[2];
    const float* ln2_s = (const float*)d_in[3];
    const float* ln2_b = (const float*)d_in[4];
    const float* wq = (const float*)d_in[5];
    const float* bq = (const float*)d_in[6];
    const float* wk = (const float*)d_in[7];
    const float* bk = (const float*)d_in[8];
    const float* wv = (const float*)d_in[9];
    const float* bv = (const float*)d_in[10];
    const float* wo = (const float*)d_in[11];
    const float* bo = (const float*)d_in[12];
    const float* rdw = (const float*)d_in[13];
    const float* ruw = (const float*)d_in[14];
    const float* w1 = (const float*)d_in[15];
    const float* b1 = (const float*)d_in[16];
    const float* w2 = (const float*)d_in[17];
    const float* b2 = (const float*)d_in[18];
    const float* ws1 = (const float*)d_in[19];
    const float* bs1 = (const float*)d_in[20];
    const float* ws2 = (const float*)d_in[21];
    const float* bs2 = (const float*)d_in[22];
    const float* fn_s = (const float*)d_in[23];
    const float* fn_b = (const float*)d_in[24];

    float* ws = (float*)d_ws;
    const size_t ND = (size_t)NTOK * DMODEL;
    const size_t PADROWS = (size_t)MAXTILE * 128;
    size_t o = 0;
    float* xb  = ws + o; o += ND;
    unsigned short* hb     = (unsigned short*)(ws + o); o += ND / 2;
    unsigned short* qkv_bf = (unsigned short*)(ws + o); o += (size_t)NTOK * 1536 / 2;
    unsigned short* vT     = (unsigned short*)(ws + o); o += ND / 2;
    unsigned short* t1b    = (unsigned short*)(ws + o); o += ND / 2;
    unsigned short* hidb   = (unsigned short*)(ws + o); o += (size_t)NTOK * HSHARED / 2;
    unsigned short* eogb   = (unsigned short*)(ws + o); o += PADROWS * DMODEL / 2;
    float* pbuf = ws + o; o += 4 * ND;                 // split-K partials (max SK=4)
    float* rdru = ws + o; o += (size_t)DMODEL * NEXP;
    float* rsc  = ws + o; o += (size_t)NTOK * NEXP;
    float* topw = ws + o; o += (size_t)NTOK * TOPK;
    float* bqkv = ws + o; o += 1536;
    int* topi = (int*)(ws + o); o += (size_t)NTOK * TOPK;
    int* pos  = (int*)(ws + o); o += (size_t)NTOK * TOPK;
    int* perm = (int*)(ws + o); o += PADROWS;
    int* stats = (int*)(ws + o); o += 256;
    int* tinfo = (int*)(ws + o); o += 512;
    int* cnt = stats;
    int* cursor = stats + 32;
    int* poff = stats + 64;
    float* sumP = (float*)(stats + 96);
    float* zacc = sumP + 32;
    unsigned short* wbf = (unsigned short*)(ws + o);
    unsigned short* wqkvt = wbf;
    unsigned short* wot  = wqkvt + 3 * (size_t)DDU;
    unsigned short* w1t  = wot + DDU;
    unsigned short* w2t  = w1t + (size_t)NEXP * DDU;
    unsigned short* ws1t = w2t + (size_t)NEXP * DDU;
    unsigned short* ws2t = ws1t + (size_t)DMODEL * HSHARED;

    float* out_x = (float*)d_out;
    float* out_aux = out_x + ND;

    hipMemcpyAsync(xb, x_in, ND * sizeof(float), hipMemcpyDeviceToDevice, stream);

    dim3 blk(256);
    dim3 gQKV(1536 / 64, NTOK / 128);           // 768 blocks
    dim3 gOP(DMODEL / 64, NTOK / 128, 2);       // 512 blocks
    dim3 gF2(DMODEL / 64, NTOK / 128, 4);       // 1024 blocks
    dim3 gHS(HSHARED / 64, NTOK / 128);         // 2048 blocks
    dim3 gE1(HEXP / 64, MAXTILE);               // 1280 blocks
    dim3 gE2(DMODEL / 64, MAXTILE);

    for (int l = 0; l < NLAYER; l++) {
        const size_t DD = (size_t)DMODEL * DMODEL;
        // ---- ALL weight prep in one launch (8 transposes + biaspack + stats zero) ----
        wtall_kernel<<<5382, blk, 0, stream>>>(
            wq + l * DD, wk + l * DD, wv + l * DD, wo + l * DD,
            w1 + (size_t)l * NEXP * DD, w2 + (size_t)l * NEXP * DD,
            ws1 + (size_t)l * DMODEL * HSHARED, ws2 + (size_t)l * HSHARED * DMODEL,
            bq + l * DMODEL, bk + l * DMODEL, bv + l * DMODEL,
            wqkvt, wot, w1t, w2t, ws1t, ws2t, bqkv, stats);
        // ---- router weight fold: rdru = rd @ ru ----
        gemm_tile<false><<<dim3(1, 8), blk, 0, stream>>>(
            rdw + (size_t)l * DMODEL * RRANK, ruw + (size_t)l * RRANK * NEXP, rdru, DMODEL, NEXP, RRANK, RRANK);

        // ---- LN1 (layer 0 only; later layers fused into F2 reduceln) ----
        if (l == 0)
            ln_kernel<1><<<NTOK / 4, blk, 0, stream>>>(xb, ln1_s, ln1_b, nullptr, hb);
        // ---- fused QKV ----
        gemm_mfma<false, false, false, false, true><<<gQKV, blk, 0, stream>>>(
            hb, wqkvt, bqkv, nullptr, qkv_bf, NTOK, 1536, DMODEL, nullptr, nullptr, nullptr, nullptr);
        // ---- V transpose ----
        vtr_kernel<<<dim3(SEQ / 64, NHEAD, BATCH), blk, 0, stream>>>(qkv_bf, vT);
        // ---- MFMA attention ----
        attn_mfma<<<dim3(SEQ / QBLK, NHEAD, BATCH), blk, 0, stream>>>(qkv_bf, vT, t1b);
        // ---- out proj: split-K=2 + fused reduce+LN2+router-scores (hb bf16 out; rsc fp32) ----
        gemm_mfma<false, false, false, false, false, 2><<<gOP, blk, 0, stream>>>(
            t1b, wot, nullptr, nullptr, pbuf, NTOK, DMODEL, DMODEL, nullptr, nullptr, nullptr, nullptr);
        reduceln_kernel<2, false, 1, true><<<NTOK / 4, blk, 0, stream>>>(
            pbuf, bo + l * DMODEL, nullptr, nullptr, nullptr, xb,
            ln2_s + l * DMODEL, ln2_b + l * DMODEL, nullptr, hb, rdru, rsc);
        // ---- router top-k + stats ----
        router_topk<<<NTOK / 256, blk, 0, stream>>>(rsc, topw, topi, cnt, sumP, zacc);
        scanaux_kernel<<<1, 64, 0, stream>>>(cnt, poff, tinfo, perm, sumP, zacc, out_aux, l);
        scatter_kernel<<<NTOK * TOPK / 256, blk, 0, stream>>>(topi, poff, cursor, perm, pos);
        // ---- expert FFN ----
        gemm_mfma<true, false, true, true, true><<<gE1, blk, 0, stream>>>(
            hb, w1t, b1 + (size_t)l * NEXP * HEXP, nullptr,
            hidb, 0, HEXP, DMODEL, perm, cnt, poff, tinfo);
        gemm_mfma<false, false, false, true, true><<<gE2, blk, 0, stream>>>(
            hidb, w2t, b2 + (size_t)l * NEXP * DMODEL, nullptr,
            eogb, 0, DMODEL, HEXP, nullptr, cnt, poff, tinfo);
        // ---- shared FFN1 ----
        gemm_mfma<true, false, false, false, true><<<gHS, blk, 0, stream>>>(
            hb, ws1t, bs1 + (size_t)l * HSHARED, nullptr,
            hidb, NTOK, HSHARED, DMODEL, nullptr, nullptr, nullptr, nullptr);
        // ---- shared FFN2: split-K=4 + fused reduce+MoE-combine+LN(next layer or final) ----
        gemm_mfma<false, false, false, false, false, 4><<<gF2, blk, 0, stream>>>(
            hidb, ws2t, nullptr, nullptr, pbuf, NTOK, DMODEL, HSHARED, nullptr, nullptr, nullptr, nullptr);
        if (l + 1 < NLAYER) {
            reduceln_kernel<4, true, 1, false><<<NTOK / 4, blk, 0, stream>>>(
                pbuf, bs2 + l * DMODEL, eogb, topw, pos, xb,
                ln1_s + (l + 1) * DMODEL, ln1_b + (l + 1) * DMODEL, nullptr, hb, nullptr, nullptr);
        } else {
            reduceln_kernel<4, true, 0, false><<<NTOK / 4, blk, 0, stream>>>(
                pbuf, bs2 + l * DMODEL, eogb, topw, pos, xb,
                fn_s, fn_b, out_x, nullptr, nullptr, nullptr);
        }
    }
}